// Round 1
// baseline (108.810 us; speedup 1.0000x reference)
//
#include <hip/hip_runtime.h>
#include <math.h>

#define D 2048
#define NTOK 16384
#define NBLK 1024
#define NT_PER_BLK 16

// ws layout (floats):
// [0..10] a_k   [16..26] b_k   [32] inv_temp   [33] alpha   [34..36] mix
// [40..63] M3 (8x3 softmaxed q3_to_group)   [64 ..) partials [67][NBLK]
#define WS_A 0
#define WS_B 16
#define WS_IT 32
#define WS_ALPHA 33
#define WS_MIX 34
#define WS_M3 40
#define WS_PART 64

__device__ __forceinline__ float wsum(float v){
#pragma unroll
  for (int m = 1; m < 64; m <<= 1) v += __shfl_xor(v, m, 64);
  return v;
}
__device__ __forceinline__ float wmax(float v){
#pragma unroll
  for (int m = 1; m < 64; m <<= 1) v = fmaxf(v, __shfl_xor(v, m, 64));
  return v;
}
__device__ __forceinline__ float rcp_fast(float x){ return __builtin_amdgcn_rcpf(x); }
__device__ __forceinline__ float tanh_fast(float x){
  // tanh(x) = 1 - 2/(exp(2x)+1); correct limits at +/-inf
  float e = __expf(2.0f * x);
  return 1.0f - 2.0f * rcp_fast(e + 1.0f);
}

// ---------------- k0: token-independent constants ----------------
__global__ __launch_bounds__(256) void k0_prep(
    const float* __restrict__ ln_w, const float* __restrict__ ln_b,
    const float* __restrict__ w_q2, const float* __restrict__ w_q3,
    const float* __restrict__ w_q6,
    const float* __restrict__ log_temp, const float* __restrict__ log_scale_mix,
    const float* __restrict__ q3_to_group, const float* __restrict__ log_wht_mix,
    float* __restrict__ ws)
{
  __shared__ float red[4];
  const int tid = threadIdx.x;
  const float* rows[11] = {w_q2, w_q2 + D,
                           w_q3, w_q3 + D, w_q3 + 2*D,
                           w_q6, w_q6 + D, w_q6 + 2*D, w_q6 + 3*D, w_q6 + 4*D, w_q6 + 5*D};
#pragma unroll
  for (int k = 0; k < 11; ++k){
    float pa = 0.f, pb = 0.f;
    for (int i = tid; i < D; i += 256){
      float w = rows[k][i];
      pa = fmaf(ln_w[i], w, pa);
      pb = fmaf(ln_b[i], w, pb);
    }
    pa = wsum(pa); pb = wsum(pb);
    __syncthreads();
    if ((tid & 63) == 0) red[tid >> 6] = pa;
    __syncthreads();
    float sa = red[0] + red[1] + red[2] + red[3];
    __syncthreads();
    if ((tid & 63) == 0) red[tid >> 6] = pb;
    __syncthreads();
    float sb = red[0] + red[1] + red[2] + red[3];
    if (tid == 0){ ws[WS_A + k] = sa; ws[WS_B + k] = sb; }
    __syncthreads();
  }
  if (tid == 0){
    float t = __expf(log_temp[0]);
    t = fminf(fmaxf(t, 0.1f), 5.0f);
    ws[WS_IT] = 1.0f / t;
    ws[WS_ALPHA] = 1.0f / (1.0f + __expf(-log_wht_mix[0]));
    float m0 = log_scale_mix[0], m1 = log_scale_mix[1], m2 = log_scale_mix[2];
    float mm = fmaxf(m0, fmaxf(m1, m2));
    float e0 = __expf(m0 - mm), e1 = __expf(m1 - mm), e2 = __expf(m2 - mm);
    float inv = 1.0f / (e0 + e1 + e2);
    ws[WS_MIX + 0] = e0 * inv; ws[WS_MIX + 1] = e1 * inv; ws[WS_MIX + 2] = e2 * inv;
    for (int r = 0; r < 8; ++r){
      float v0 = q3_to_group[r*3+0], v1 = q3_to_group[r*3+1], v2 = q3_to_group[r*3+2];
      float mx = fmaxf(v0, fmaxf(v1, v2));
      float f0 = __expf(v0 - mx), f1 = __expf(v1 - mx), f2 = __expf(v2 - mx);
      float iv = 1.0f / (f0 + f1 + f2);
      ws[WS_M3 + r*3 + 0] = f0 * iv;
      ws[WS_M3 + r*3 + 1] = f1 * iv;
      ws[WS_M3 + r*3 + 2] = f2 * iv;
    }
  }
}

// ---------------- k1: main per-token kernel ----------------
// 1024 blocks x 256 threads (4 waves). Each wave: 4 tokens, full D traversal.
__global__ __launch_bounds__(256) void k1_main(
    const float* __restrict__ x,
    const float* __restrict__ ln_w,
    const float* __restrict__ w_q2, const float* __restrict__ w_q3,
    const float* __restrict__ w_q6,
    const float* __restrict__ ws,
    float* __restrict__ gout, float* __restrict__ hout, float* __restrict__ part)
{
  const int tid  = threadIdx.x;
  const int lane = tid & 63;
  const int wid  = tid >> 6;
  const int blk  = blockIdx.x;
  const int tok0 = blk * NT_PER_BLK + wid * 4;

  float sum[4] = {0,0,0,0};
  float sq [4] = {0,0,0,0};
  float t[11][4];
#pragma unroll
  for (int k = 0; k < 11; ++k){
#pragma unroll
    for (int j = 0; j < 4; ++j) t[k][j] = 0.f;
  }

  const int off0 = lane * 4;
  const float* xp = x + (size_t)tok0 * D + off0;

#pragma unroll 2
  for (int c = 0; c < 8; ++c){
    const int off = c * 256;
    float4 lw  = *(const float4*)(ln_w + off0 + off);
    float4 xv0 = *(const float4*)(xp + off);
    float4 xv1 = *(const float4*)(xp + 1*D + off);
    float4 xv2 = *(const float4*)(xp + 2*D + off);
    float4 xv3 = *(const float4*)(xp + 3*D + off);
    float4 wv[11];
    wv[0] = *(const float4*)(w_q2 + off0 + off);
    wv[1] = *(const float4*)(w_q2 + D + off0 + off);
    wv[2] = *(const float4*)(w_q3 + off0 + off);
    wv[3] = *(const float4*)(w_q3 + D + off0 + off);
    wv[4] = *(const float4*)(w_q3 + 2*D + off0 + off);
#pragma unroll
    for (int q = 0; q < 6; ++q) wv[5+q] = *(const float4*)(w_q6 + q*D + off0 + off);

    const float* lwf = (const float*)&lw;
    const float* xf0 = (const float*)&xv0;
    const float* xf1 = (const float*)&xv1;
    const float* xf2 = (const float*)&xv2;
    const float* xf3 = (const float*)&xv3;
#pragma unroll
    for (int e = 0; e < 4; ++e){
      float xe0 = xf0[e], xe1 = xf1[e], xe2 = xf2[e], xe3 = xf3[e];
      sum[0] += xe0; sum[1] += xe1; sum[2] += xe2; sum[3] += xe3;
      sq[0] = fmaf(xe0, xe0, sq[0]);
      sq[1] = fmaf(xe1, xe1, sq[1]);
      sq[2] = fmaf(xe2, xe2, sq[2]);
      sq[3] = fmaf(xe3, xe3, sq[3]);
      float lwe = lwf[e];
      float y0 = xe0*lwe, y1 = xe1*lwe, y2 = xe2*lwe, y3 = xe3*lwe;
#pragma unroll
      for (int k = 0; k < 11; ++k){
        float we = ((const float*)&wv[k])[e];
        t[k][0] = fmaf(y0, we, t[k][0]);
        t[k][1] = fmaf(y1, we, t[k][1]);
        t[k][2] = fmaf(y2, we, t[k][2]);
        t[k][3] = fmaf(y3, we, t[k][3]);
      }
    }
  }

  // cross-lane reductions (all lanes end with totals)
#pragma unroll
  for (int j = 0; j < 4; ++j){ sum[j] = wsum(sum[j]); sq[j] = wsum(sq[j]); }
#pragma unroll
  for (int k = 0; k < 11; ++k){
#pragma unroll
    for (int j = 0; j < 4; ++j) t[k][j] = wsum(t[k][j]);
  }

  // constants (uniform, small, L1-resident)
  float a[11], bb[11];
#pragma unroll
  for (int k = 0; k < 11; ++k){ a[k] = ws[WS_A + k]; bb[k] = ws[WS_B + k]; }
  const float it    = ws[WS_IT];
  const float alpha = ws[WS_ALPHA];
  const float mix0 = ws[WS_MIX], mix1 = ws[WS_MIX+1], mix2 = ws[WS_MIX+2];
  float M3[8][3];
#pragma unroll
  for (int r = 0; r < 8; ++r){
#pragma unroll
    for (int g = 0; g < 3; ++g) M3[r][g] = ws[WS_M3 + r*3 + g];
  }

  // per-lane hexagram row: signs, cos-anchor row, wht row -> fused M6 row
  float sgn[6];
#pragma unroll
  for (int j = 0; j < 6; ++j) sgn[j] = ((lane >> (5 - j)) & 1) ? 1.0f : -1.0f;
  const float C5 = 0.44721359549995793f; // 1/sqrt(5)
  const float A0[6] = { C5,  C5,  C5,  C5,  C5, 0.f };
  const float A1[6] = {-0.5f, 0.5f, -0.5f, 0.f, 0.f, 0.5f};
  const float A2[6] = {-C5, -C5, 0.f, -C5, -C5, -C5};
  float cs0 = 0.f, cs1 = 0.f, cs2 = 0.f;
#pragma unroll
  for (int j = 0; j < 6; ++j){
    cs0 = fmaf(sgn[j], A0[j], cs0);
    cs1 = fmaf(sgn[j], A1[j], cs1);
    cs2 = fmaf(sgn[j], A2[j], cs2);
  }
  const int pc = __popc(lane);
  const float w7 = 1.0f / 7.0f;
  float wh0 = (pc >= 5) ? w7   : 0.f;
  float wh1 = (pc == 3) ? 0.05f: 0.f;
  float wh2 = (pc <= 1) ? w7   : 0.f;
  float m60 = (1.f - alpha)*cs0 + alpha*wh0;
  float m61 = (1.f - alpha)*cs1 + alpha*wh1;
  float m62 = (1.f - alpha)*cs2 + alpha*wh2;

  float hsum = 0.f, ga0 = 0.f, ga1 = 0.f, ga2 = 0.f;

#pragma unroll
  for (int j = 0; j < 4; ++j){
    const int tok = tok0 + j;
    float mean = sum[j] * (1.0f / D);
    float var  = fmaf(sq[j], 1.0f / D, -mean * mean);
    float rr   = rsqrtf(var + 1e-5f);
    float u[11];
#pragma unroll
    for (int k = 0; k < 11; ++k){
      float d = fmaf(-mean, a[k], t[k][j]);   // t - mean*a
      u[k] = tanh_fast(fmaf(rr, d, bb[k]));
    }

    // ---- Q2 (4 vertices, redundant per lane) ----
    float p01 = u[0] + u[1], m01 = u[0] - u[1];
    float l0 = -p01*it, l1 = -m01*it, l2 = m01*it, l3 = p01*it;
    float mx2 = fmaxf(fmaxf(l0, l1), fmaxf(l2, l3));
    float e0 = __expf(l0-mx2), e1 = __expf(l1-mx2), e2 = __expf(l2-mx2), e3 = __expf(l3-mx2);
    float i2 = rcp_fast(e0 + e1 + e2 + e3);
    float s2g0 = e3 * i2, s2g1 = (e1 + e2) * i2, s2g2 = e0 * i2;

    // ---- Q3 (8 vertices, redundant per lane) ----
    float l3v[8]; float mx3 = -1e30f;
#pragma unroll
    for (int v = 0; v < 8; ++v){
      float acc = ((v & 4) ? u[2] : -u[2]) + ((v & 2) ? u[3] : -u[3]) + ((v & 1) ? u[4] : -u[4]);
      l3v[v] = acc * it;
      mx3 = fmaxf(mx3, l3v[v]);
    }
    float w3[8]; float se3 = 0.f;
#pragma unroll
    for (int v = 0; v < 8; ++v){ w3[v] = __expf(l3v[v] - mx3); se3 += w3[v]; }
    float i3 = rcp_fast(se3);
    float s3g0 = 0.f, s3g1 = 0.f, s3g2 = 0.f;
#pragma unroll
    for (int v = 0; v < 8; ++v){
      s3g0 = fmaf(w3[v], M3[v][0], s3g0);
      s3g1 = fmaf(w3[v], M3[v][1], s3g1);
      s3g2 = fmaf(w3[v], M3[v][2], s3g2);
    }
    s3g0 *= i3; s3g1 *= i3; s3g2 *= i3;

    // ---- Q6 (64 vertices, lane-parallel) ----
    float lg = 0.f;
#pragma unroll
    for (int jj = 0; jj < 6; ++jj) lg = fmaf(sgn[jj], u[5 + jj], lg);
    lg *= it;
    float mx6 = wmax(lg);
    float p   = __expf(lg - mx6);
    float se6 = wsum(p);
    float hw  = p * rcp_fast(se6);
    hout[(size_t)tok * 64 + lane] = hw;
    hsum += hw;
    float s6g0 = wsum(hw * m60);
    float s6g1 = wsum(hw * m61);
    float s6g2 = wsum(hw * m62);

    // ---- combine + group softmax ----
    float g0 = mix0*s2g0 + mix1*s3g0 + mix2*s6g0;
    float g1 = mix0*s2g1 + mix1*s3g1 + mix2*s6g1;
    float g2 = mix0*s2g2 + mix1*s3g2 + mix2*s6g2;
    float gm = fmaxf(g0, fmaxf(g1, g2));
    float x0 = __expf(g0-gm), x1 = __expf(g1-gm), x2 = __expf(g2-gm);
    float gi = rcp_fast(x0 + x1 + x2);
    float gw0 = x0*gi, gw1 = x1*gi, gw2 = x2*gi;
    ga0 += gw0; ga1 += gw1; ga2 += gw2;
    if (lane < 3){
      float val = (lane == 0) ? gw0 : (lane == 1) ? gw1 : gw2;
      gout[(size_t)tok * 3 + lane] = val;
    }
  }

  // block-level partials for lb_loss
  __shared__ float lred[4][67];
  lred[wid][lane] = hsum;
  if (lane < 3){
    float val = (lane == 0) ? ga0 : (lane == 1) ? ga1 : ga2;
    lred[wid][64 + lane] = val;
  }
  __syncthreads();
  if (tid < 67){
    float v = lred[0][tid] + lred[1][tid] + lred[2][tid] + lred[3][tid];
    part[(size_t)tid * NBLK + blk] = v;
  }
}

// ---------------- k2: final reduction + lb_loss ----------------
__global__ __launch_bounds__(256) void k2_loss(const float* __restrict__ part,
                                               float* __restrict__ lout)
{
  __shared__ float sums[67];
  __shared__ float red[4];
  const int tid = threadIdx.x;
  for (int jv = 0; jv < 67; ++jv){
    float v = 0.f;
#pragma unroll
    for (int b = 0; b < NBLK/256; ++b) v += part[(size_t)jv * NBLK + b*256 + tid];
    v = wsum(v);
    __syncthreads();
    if ((tid & 63) == 0) red[tid >> 6] = v;
    __syncthreads();
    if (tid == 0) sums[jv] = red[0] + red[1] + red[2] + red[3];
  }
  __syncthreads();
  if (tid == 0){
    const float inv = 1.0f / (float)NTOK;
    float L = 0.f;
    for (int v = 0; v < 64; ++v){ float m = sums[v] * inv; L += 0.1f * m * logf(m + 1e-8f); }
    for (int g = 0; g < 3; ++g){ float m = sums[64 + g] * inv; L += m * logf(m + 1e-8f); }
    lout[0] = L;
  }
}

extern "C" void kernel_launch(void* const* d_in, const int* in_sizes, int n_in,
                              void* d_out, int out_size, void* d_ws, size_t ws_size,
                              hipStream_t stream)
{
  const float* x             = (const float*)d_in[0];
  const float* ln_w          = (const float*)d_in[1];
  const float* ln_b          = (const float*)d_in[2];
  const float* w_q2          = (const float*)d_in[3];
  const float* w_q3          = (const float*)d_in[4];
  const float* w_q6          = (const float*)d_in[5];
  const float* log_temp      = (const float*)d_in[6];
  const float* log_scale_mix = (const float*)d_in[7];
  const float* q3_to_group   = (const float*)d_in[8];
  const float* log_wht_mix   = (const float*)d_in[9];

  float* out  = (float*)d_out;
  float* gout = out;                                    // (B,T,3)
  float* hout = out + (size_t)NTOK * 3;                 // (B,T,64)
  float* lout = out + (size_t)NTOK * 3 + (size_t)NTOK * 64; // scalar
  float* ws   = (float*)d_ws;

  k0_prep<<<1, 256, 0, stream>>>(ln_w, ln_b, w_q2, w_q3, w_q6,
                                 log_temp, log_scale_mix, q3_to_group, log_wht_mix, ws);
  k1_main<<<NBLK, 256, 0, stream>>>(x, ln_w, w_q2, w_q3, w_q6, ws,
                                    gout, hout, ws + WS_PART);
  k2_loss<<<1, 256, 0, stream>>>(ws + WS_PART, lout);
}

// Round 2
// 91.327 us; speedup vs baseline: 1.1914x; 1.1914x over previous
//
#include <hip/hip_runtime.h>
#include <math.h>

#define D 2048
#define NTOK 16384
#define NROW 11
#define MROWS (NROW * D)          // 22528 floats = 88 KB
#define K1_BLOCKS 256
#define TOK_PER_BLOCK 64

// ws float layout:
// [0..10] a_k   [16..26] b_k   [32] inv_temp  [33] alpha  [34..36] mix
// [40..63] M3 (8x3)  [64 .. 64+22528) merged W'  [WS_PART ..) partials [67][256]
#define WS_A 0
#define WS_B 16
#define WS_IT 32
#define WS_ALPHA 33
#define WS_MIX 34
#define WS_M3 40
#define WS_MERGED 64
#define WS_PART (WS_MERGED + MROWS)

__device__ __forceinline__ float wsum(float v){
#pragma unroll
  for (int m = 1; m < 64; m <<= 1) v += __shfl_xor(v, m, 64);
  return v;
}
__device__ __forceinline__ float wmax(float v){
#pragma unroll
  for (int m = 1; m < 64; m <<= 1) v = fmaxf(v, __shfl_xor(v, m, 64));
  return v;
}
__device__ __forceinline__ float rcp_fast(float x){ return __builtin_amdgcn_rcpf(x); }
__device__ __forceinline__ float tanh_fast(float x){
  float e = __expf(2.0f * x);
  return 1.0f - 2.0f * rcp_fast(e + 1.0f);
}

// ---------------- k0: merge rows + constants (12 blocks) ----------------
__global__ __launch_bounds__(256) void k0_prep(
    const float* __restrict__ ln_w, const float* __restrict__ ln_b,
    const float* __restrict__ w_q2, const float* __restrict__ w_q3,
    const float* __restrict__ w_q6,
    const float* __restrict__ log_temp, const float* __restrict__ log_scale_mix,
    const float* __restrict__ q3_to_group, const float* __restrict__ log_wht_mix,
    float* __restrict__ ws)
{
  const int tid = threadIdx.x;
  const int k = blockIdx.x;
  if (k < NROW){
    const float* row = (k < 2) ? (w_q2 + (size_t)k * D)
                     : (k < 5) ? (w_q3 + (size_t)(k - 2) * D)
                               : (w_q6 + (size_t)(k - 5) * D);
    float pa = 0.f, pb = 0.f;
    for (int i = tid; i < D; i += 256){
      float w = row[i];
      float m = ln_w[i] * w;
      ws[WS_MERGED + k * D + i] = m;
      pa += m;                       // a_k = sum(ln_w * w) = sum(merged)
      pb = fmaf(ln_b[i], w, pb);     // b_k = sum(ln_b * w)
    }
    __shared__ float red[8];
    pa = wsum(pa); pb = wsum(pb);
    if ((tid & 63) == 0){ red[tid >> 6] = pa; red[4 + (tid >> 6)] = pb; }
    __syncthreads();
    if (tid == 0){
      ws[WS_A + k] = red[0] + red[1] + red[2] + red[3];
      ws[WS_B + k] = red[4] + red[5] + red[6] + red[7];
    }
  } else if (tid == 0){
    float t = __expf(log_temp[0]);
    t = fminf(fmaxf(t, 0.1f), 5.0f);
    ws[WS_IT] = 1.0f / t;
    ws[WS_ALPHA] = 1.0f / (1.0f + __expf(-log_wht_mix[0]));
    float m0 = log_scale_mix[0], m1 = log_scale_mix[1], m2 = log_scale_mix[2];
    float mm = fmaxf(m0, fmaxf(m1, m2));
    float e0 = __expf(m0 - mm), e1 = __expf(m1 - mm), e2 = __expf(m2 - mm);
    float inv = 1.0f / (e0 + e1 + e2);
    ws[WS_MIX + 0] = e0 * inv; ws[WS_MIX + 1] = e1 * inv; ws[WS_MIX + 2] = e2 * inv;
    for (int r = 0; r < 8; ++r){
      float v0 = q3_to_group[r*3+0], v1 = q3_to_group[r*3+1], v2 = q3_to_group[r*3+2];
      float mx = fmaxf(v0, fmaxf(v1, v2));
      float f0 = __expf(v0 - mx), f1 = __expf(v1 - mx), f2 = __expf(v2 - mx);
      float iv = 1.0f / (f0 + f1 + f2);
      ws[WS_M3 + r*3 + 0] = f0 * iv;
      ws[WS_M3 + r*3 + 1] = f1 * iv;
      ws[WS_M3 + r*3 + 2] = f2 * iv;
    }
  }
}

// ---------------- k1: main per-token kernel ----------------
// 256 blocks x 1024 threads (16 waves). One block per CU. W' staged in LDS.
// Each wave: 4 tokens, global loads are x only (prefetched 1 chunk ahead).
__global__ __launch_bounds__(1024) void k1_main(
    const float* __restrict__ x, const float* __restrict__ ws,
    float* __restrict__ gout, float* __restrict__ hout, float* __restrict__ part)
{
  __shared__ float sW[MROWS];
  __shared__ float lred[16][68];
  const int tid  = threadIdx.x;
  const int lane = tid & 63;
  const int wid  = tid >> 6;
  const int blk  = blockIdx.x;

  // stage merged W' into LDS (6 float4 iterations per thread)
  for (int idx = tid * 4; idx < MROWS; idx += 4096)
    *(float4*)(sW + idx) = *(const float4*)(ws + WS_MERGED + idx);
  __syncthreads();

  const int tok0 = blk * TOK_PER_BLOCK + wid * 4;
  const int off0 = lane * 4;
  const float* xp0 = x + (size_t)tok0 * D + off0;
  const float* xp1 = xp0 + D;
  const float* xp2 = xp0 + 2 * D;
  const float* xp3 = xp0 + 3 * D;

  float sum[4] = {0,0,0,0}, sq[4] = {0,0,0,0};
  float t[NROW][4];
#pragma unroll
  for (int k = 0; k < NROW; ++k){ t[k][0]=t[k][1]=t[k][2]=t[k][3]=0.f; }

  float4 xc0 = *(const float4*)xp0;
  float4 xc1 = *(const float4*)xp1;
  float4 xc2 = *(const float4*)xp2;
  float4 xc3 = *(const float4*)xp3;

#pragma unroll 1
  for (int c = 0; c < 8; ++c){
    const int off = c * 256;
    float4 xn0, xn1, xn2, xn3;
    if (c < 7){
      xn0 = *(const float4*)(xp0 + off + 256);
      xn1 = *(const float4*)(xp1 + off + 256);
      xn2 = *(const float4*)(xp2 + off + 256);
      xn3 = *(const float4*)(xp3 + off + 256);
    }
    const float* wb = sW + off0 + off;
    // ---- phase A: rows 0..5 + sums/sq ----
    {
      float4 wv0 = *(const float4*)(wb + 0*D);
      float4 wv1 = *(const float4*)(wb + 1*D);
      float4 wv2 = *(const float4*)(wb + 2*D);
      float4 wv3 = *(const float4*)(wb + 3*D);
      float4 wv4 = *(const float4*)(wb + 4*D);
      float4 wv5 = *(const float4*)(wb + 5*D);
#pragma unroll
      for (int e = 0; e < 4; ++e){
        float x0 = ((const float*)&xc0)[e];
        float x1 = ((const float*)&xc1)[e];
        float x2 = ((const float*)&xc2)[e];
        float x3 = ((const float*)&xc3)[e];
        sum[0] += x0; sum[1] += x1; sum[2] += x2; sum[3] += x3;
        sq[0] = fmaf(x0,x0,sq[0]); sq[1] = fmaf(x1,x1,sq[1]);
        sq[2] = fmaf(x2,x2,sq[2]); sq[3] = fmaf(x3,x3,sq[3]);
        float w;
        w = ((const float*)&wv0)[e]; t[0][0]=fmaf(x0,w,t[0][0]); t[0][1]=fmaf(x1,w,t[0][1]); t[0][2]=fmaf(x2,w,t[0][2]); t[0][3]=fmaf(x3,w,t[0][3]);
        w = ((const float*)&wv1)[e]; t[1][0]=fmaf(x0,w,t[1][0]); t[1][1]=fmaf(x1,w,t[1][1]); t[1][2]=fmaf(x2,w,t[1][2]); t[1][3]=fmaf(x3,w,t[1][3]);
        w = ((const float*)&wv2)[e]; t[2][0]=fmaf(x0,w,t[2][0]); t[2][1]=fmaf(x1,w,t[2][1]); t[2][2]=fmaf(x2,w,t[2][2]); t[2][3]=fmaf(x3,w,t[2][3]);
        w = ((const float*)&wv3)[e]; t[3][0]=fmaf(x0,w,t[3][0]); t[3][1]=fmaf(x1,w,t[3][1]); t[3][2]=fmaf(x2,w,t[3][2]); t[3][3]=fmaf(x3,w,t[3][3]);
        w = ((const float*)&wv4)[e]; t[4][0]=fmaf(x0,w,t[4][0]); t[4][1]=fmaf(x1,w,t[4][1]); t[4][2]=fmaf(x2,w,t[4][2]); t[4][3]=fmaf(x3,w,t[4][3]);
        w = ((const float*)&wv5)[e]; t[5][0]=fmaf(x0,w,t[5][0]); t[5][1]=fmaf(x1,w,t[5][1]); t[5][2]=fmaf(x2,w,t[5][2]); t[5][3]=fmaf(x3,w,t[5][3]);
      }
    }
    // ---- phase B: rows 6..10 ----
    {
      float4 wv6 = *(const float4*)(wb + 6*D);
      float4 wv7 = *(const float4*)(wb + 7*D);
      float4 wv8 = *(const float4*)(wb + 8*D);
      float4 wv9 = *(const float4*)(wb + 9*D);
      float4 wvA = *(const float4*)(wb + 10*D);
#pragma unroll
      for (int e = 0; e < 4; ++e){
        float x0 = ((const float*)&xc0)[e];
        float x1 = ((const float*)&xc1)[e];
        float x2 = ((const float*)&xc2)[e];
        float x3 = ((const float*)&xc3)[e];
        float w;
        w = ((const float*)&wv6)[e]; t[6][0]=fmaf(x0,w,t[6][0]); t[6][1]=fmaf(x1,w,t[6][1]); t[6][2]=fmaf(x2,w,t[6][2]); t[6][3]=fmaf(x3,w,t[6][3]);
        w = ((const float*)&wv7)[e]; t[7][0]=fmaf(x0,w,t[7][0]); t[7][1]=fmaf(x1,w,t[7][1]); t[7][2]=fmaf(x2,w,t[7][2]); t[7][3]=fmaf(x3,w,t[7][3]);
        w = ((const float*)&wv8)[e]; t[8][0]=fmaf(x0,w,t[8][0]); t[8][1]=fmaf(x1,w,t[8][1]); t[8][2]=fmaf(x2,w,t[8][2]); t[8][3]=fmaf(x3,w,t[8][3]);
        w = ((const float*)&wv9)[e]; t[9][0]=fmaf(x0,w,t[9][0]); t[9][1]=fmaf(x1,w,t[9][1]); t[9][2]=fmaf(x2,w,t[9][2]); t[9][3]=fmaf(x3,w,t[9][3]);
        w = ((const float*)&wvA)[e]; t[10][0]=fmaf(x0,w,t[10][0]); t[10][1]=fmaf(x1,w,t[10][1]); t[10][2]=fmaf(x2,w,t[10][2]); t[10][3]=fmaf(x3,w,t[10][3]);
      }
    }
    if (c < 7){ xc0 = xn0; xc1 = xn1; xc2 = xn2; xc3 = xn3; }
  }

  // cross-lane reductions (broadcast totals to all lanes)
#pragma unroll
  for (int j = 0; j < 4; ++j){ sum[j] = wsum(sum[j]); sq[j] = wsum(sq[j]); }
#pragma unroll
  for (int k = 0; k < NROW; ++k){
#pragma unroll
    for (int j = 0; j < 4; ++j) t[k][j] = wsum(t[k][j]);
  }

  // constants
  float a[NROW], bb[NROW];
#pragma unroll
  for (int k = 0; k < NROW; ++k){ a[k] = ws[WS_A + k]; bb[k] = ws[WS_B + k]; }
  const float it    = ws[WS_IT];
  const float alpha = ws[WS_ALPHA];
  const float mix0 = ws[WS_MIX], mix1 = ws[WS_MIX+1], mix2 = ws[WS_MIX+2];
  float M3[8][3];
#pragma unroll
  for (int r = 0; r < 8; ++r){
#pragma unroll
    for (int g = 0; g < 3; ++g) M3[r][g] = ws[WS_M3 + r*3 + g];
  }

  // per-lane hexagram row: signs, fused (cos-anchor, wht) row
  float sgn[6];
#pragma unroll
  for (int j = 0; j < 6; ++j) sgn[j] = ((lane >> (5 - j)) & 1) ? 1.0f : -1.0f;
  const float C5 = 0.44721359549995793f; // 1/sqrt(5)
  const float A0[6] = { C5,  C5,  C5,  C5,  C5, 0.f };
  const float A1[6] = {-0.5f, 0.5f, -0.5f, 0.f, 0.f, 0.5f};
  const float A2[6] = {-C5, -C5, 0.f, -C5, -C5, -C5};
  float cs0 = 0.f, cs1 = 0.f, cs2 = 0.f;
#pragma unroll
  for (int j = 0; j < 6; ++j){
    cs0 = fmaf(sgn[j], A0[j], cs0);
    cs1 = fmaf(sgn[j], A1[j], cs1);
    cs2 = fmaf(sgn[j], A2[j], cs2);
  }
  const int pc = __popc(lane);
  const float w7 = 1.0f / 7.0f;
  float wh0 = (pc >= 5) ? w7   : 0.f;
  float wh1 = (pc == 3) ? 0.05f: 0.f;
  float wh2 = (pc <= 1) ? w7   : 0.f;
  float m60 = (1.f - alpha)*cs0 + alpha*wh0;
  float m61 = (1.f - alpha)*cs1 + alpha*wh1;
  float m62 = (1.f - alpha)*cs2 + alpha*wh2;

  float hsum = 0.f, ga0 = 0.f, ga1 = 0.f, ga2 = 0.f;

#pragma unroll
  for (int j = 0; j < 4; ++j){
    const int tok = tok0 + j;
    float mean = sum[j] * (1.0f / D);
    float var  = fmaf(sq[j], 1.0f / D, -mean * mean);
    float rr   = rsqrtf(var + 1e-5f);
    float u[NROW];
#pragma unroll
    for (int k = 0; k < NROW; ++k){
      float d = fmaf(-mean, a[k], t[k][j]);
      u[k] = tanh_fast(fmaf(rr, d, bb[k]));
    }

    // ---- Q2 ----
    float p01 = u[0] + u[1], m01 = u[0] - u[1];
    float l0 = -p01*it, l1 = -m01*it, l2 = m01*it, l3 = p01*it;
    float mx2 = fmaxf(fmaxf(l0, l1), fmaxf(l2, l3));
    float e0 = __expf(l0-mx2), e1 = __expf(l1-mx2), e2 = __expf(l2-mx2), e3 = __expf(l3-mx2);
    float i2 = rcp_fast(e0 + e1 + e2 + e3);
    float s2g0 = e3 * i2, s2g1 = (e1 + e2) * i2, s2g2 = e0 * i2;

    // ---- Q3 ----
    float l3v[8]; float mx3 = -1e30f;
#pragma unroll
    for (int v = 0; v < 8; ++v){
      float acc = ((v & 4) ? u[2] : -u[2]) + ((v & 2) ? u[3] : -u[3]) + ((v & 1) ? u[4] : -u[4]);
      l3v[v] = acc * it;
      mx3 = fmaxf(mx3, l3v[v]);
    }
    float w3[8]; float se3 = 0.f;
#pragma unroll
    for (int v = 0; v < 8; ++v){ w3[v] = __expf(l3v[v] - mx3); se3 += w3[v]; }
    float i3 = rcp_fast(se3);
    float s3g0 = 0.f, s3g1 = 0.f, s3g2 = 0.f;
#pragma unroll
    for (int v = 0; v < 8; ++v){
      s3g0 = fmaf(w3[v], M3[v][0], s3g0);
      s3g1 = fmaf(w3[v], M3[v][1], s3g1);
      s3g2 = fmaf(w3[v], M3[v][2], s3g2);
    }
    s3g0 *= i3; s3g1 *= i3; s3g2 *= i3;

    // ---- Q6 (lane-parallel over 64 vertices) ----
    float lg = 0.f;
#pragma unroll
    for (int jj = 0; jj < 6; ++jj) lg = fmaf(sgn[jj], u[5 + jj], lg);
    lg *= it;
    float mx6 = wmax(lg);
    float p   = __expf(lg - mx6);
    float se6 = wsum(p);
    float hw  = p * rcp_fast(se6);
    hout[(size_t)tok * 64 + lane] = hw;
    hsum += hw;
    float s6g0 = wsum(hw * m60);
    float s6g1 = wsum(hw * m61);
    float s6g2 = wsum(hw * m62);

    // ---- combine + group softmax ----
    float g0 = mix0*s2g0 + mix1*s3g0 + mix2*s6g0;
    float g1 = mix0*s2g1 + mix1*s3g1 + mix2*s6g1;
    float g2 = mix0*s2g2 + mix1*s3g2 + mix2*s6g2;
    float gm = fmaxf(g0, fmaxf(g1, g2));
    float y0 = __expf(g0-gm), y1 = __expf(g1-gm), y2 = __expf(g2-gm);
    float gi = rcp_fast(y0 + y1 + y2);
    float gw0 = y0*gi, gw1 = y1*gi, gw2 = y2*gi;
    ga0 += gw0; ga1 += gw1; ga2 += gw2;
    if (lane < 3){
      float val = (lane == 0) ? gw0 : (lane == 1) ? gw1 : gw2;
      gout[(size_t)tok * 3 + lane] = val;
    }
  }

  // block partials for lb_loss
  lred[wid][lane] = hsum;
  if (lane < 3){
    float val = (lane == 0) ? ga0 : (lane == 1) ? ga1 : ga2;
    lred[wid][64 + lane] = val;
  }
  __syncthreads();
  if (tid < 67){
    float v = 0.f;
#pragma unroll
    for (int r = 0; r < 16; ++r) v += lred[r][tid];
    part[tid * K1_BLOCKS + blk] = v;
  }
}

// ---------------- k2: final reduction + lb_loss ----------------
__global__ __launch_bounds__(256) void k2_loss(const float* __restrict__ part,
                                               float* __restrict__ lout)
{
  __shared__ float sums[68];
  const int tid = threadIdx.x;
  const int lane = tid & 63;
  const int wid  = tid >> 6;
  for (int jv = wid; jv < 67; jv += 4){
    const float* p = part + jv * K1_BLOCKS;
    float v = p[lane] + p[lane + 64] + p[lane + 128] + p[lane + 192];
    v = wsum(v);
    if (lane == 0) sums[jv] = v;
  }
  __syncthreads();
  if (wid == 0){
    const float inv = 1.0f / (float)NTOK;
    float mh = sums[lane] * inv;
    float term = 0.1f * mh * logf(mh + 1e-8f);
    if (lane < 3){
      float mg = sums[64 + lane] * inv;
      term += mg * logf(mg + 1e-8f);
    }
    float L = wsum(term);
    if (lane == 0) lout[0] = L;
  }
}

extern "C" void kernel_launch(void* const* d_in, const int* in_sizes, int n_in,
                              void* d_out, int out_size, void* d_ws, size_t ws_size,
                              hipStream_t stream)
{
  const float* x             = (const float*)d_in[0];
  const float* ln_w          = (const float*)d_in[1];
  const float* ln_b          = (const float*)d_in[2];
  const float* w_q2          = (const float*)d_in[3];
  const float* w_q3          = (const float*)d_in[4];
  const float* w_q6          = (const float*)d_in[5];
  const float* log_temp      = (const float*)d_in[6];
  const float* log_scale_mix = (const float*)d_in[7];
  const float* q3_to_group   = (const float*)d_in[8];
  const float* log_wht_mix   = (const float*)d_in[9];

  float* out  = (float*)d_out;
  float* gout = out;                                        // (B,T,3)
  float* hout = out + (size_t)NTOK * 3;                     // (B,T,64)
  float* lout = out + (size_t)NTOK * 3 + (size_t)NTOK * 64; // scalar
  float* ws   = (float*)d_ws;

  k0_prep<<<12, 256, 0, stream>>>(ln_w, ln_b, w_q2, w_q3, w_q6,
                                  log_temp, log_scale_mix, q3_to_group, log_wht_mix, ws);
  k1_main<<<K1_BLOCKS, 1024, 0, stream>>>(x, ws, gout, hout, ws + WS_PART);
  k2_loss<<<1, 256, 0, stream>>>(ws + WS_PART, lout);
}

// Round 3
// 88.322 us; speedup vs baseline: 1.2320x; 1.0340x over previous
//
#include <hip/hip_runtime.h>
#include <math.h>

#define D 2048
#define NTOK 16384
#define NROW 11
#define MROWS (NROW * D)          // 22528 floats = 88 KB
#define K1_BLOCKS 256
#define TOK_PER_BLOCK 64

// ws float layout:
// [0..10] a_k   [16..26] b_k   [32] inv_temp  [33] alpha  [34..36] mix
// [40..63] M3 (8x3)  [64 .. 64+22528) merged W'  [WS_PART ..) partials [67][256]
#define WS_A 0
#define WS_B 16
#define WS_IT 32
#define WS_ALPHA 33
#define WS_MIX 34
#define WS_M3 40
#define WS_MERGED 64
#define WS_PART (WS_MERGED + MROWS)

__device__ __forceinline__ float wsum(float v){
#pragma unroll
  for (int m = 1; m < 64; m <<= 1) v += __shfl_xor(v, m, 64);
  return v;
}
__device__ __forceinline__ float wmax(float v){
#pragma unroll
  for (int m = 1; m < 64; m <<= 1) v = fmaxf(v, __shfl_xor(v, m, 64));
  return v;
}
__device__ __forceinline__ float rcp_fast(float x){ return __builtin_amdgcn_rcpf(x); }
__device__ __forceinline__ float tanh_fast(float x){
  float e = __expf(2.0f * x);
  return 1.0f - 2.0f * rcp_fast(e + 1.0f);
}

// ---------------- k0: merge rows + constants (12 blocks) ----------------
__global__ __launch_bounds__(256) void k0_prep(
    const float* __restrict__ ln_w, const float* __restrict__ ln_b,
    const float* __restrict__ w_q2, const float* __restrict__ w_q3,
    const float* __restrict__ w_q6,
    const float* __restrict__ log_temp, const float* __restrict__ log_scale_mix,
    const float* __restrict__ q3_to_group, const float* __restrict__ log_wht_mix,
    float* __restrict__ ws)
{
  const int tid = threadIdx.x;
  const int k = blockIdx.x;
  if (k < NROW){
    const float* row = (k < 2) ? (w_q2 + (size_t)k * D)
                     : (k < 5) ? (w_q3 + (size_t)(k - 2) * D)
                               : (w_q6 + (size_t)(k - 5) * D);
    float pa = 0.f, pb = 0.f;
    for (int i = tid; i < D; i += 256){
      float w = row[i];
      float m = ln_w[i] * w;
      ws[WS_MERGED + k * D + i] = m;
      pa += m;                       // a_k = sum(ln_w * w)
      pb = fmaf(ln_b[i], w, pb);     // b_k = sum(ln_b * w)
    }
    __shared__ float red[8];
    pa = wsum(pa); pb = wsum(pb);
    if ((tid & 63) == 0){ red[tid >> 6] = pa; red[4 + (tid >> 6)] = pb; }
    __syncthreads();
    if (tid == 0){
      ws[WS_A + k] = red[0] + red[1] + red[2] + red[3];
      ws[WS_B + k] = red[4] + red[5] + red[6] + red[7];
    }
  } else if (tid == 0){
    float t = __expf(log_temp[0]);
    t = fminf(fmaxf(t, 0.1f), 5.0f);
    ws[WS_IT] = 1.0f / t;
    ws[WS_ALPHA] = 1.0f / (1.0f + __expf(-log_wht_mix[0]));
    float m0 = log_scale_mix[0], m1 = log_scale_mix[1], m2 = log_scale_mix[2];
    float mm = fmaxf(m0, fmaxf(m1, m2));
    float e0 = __expf(m0 - mm), e1 = __expf(m1 - mm), e2 = __expf(m2 - mm);
    float inv = 1.0f / (e0 + e1 + e2);
    ws[WS_MIX + 0] = e0 * inv; ws[WS_MIX + 1] = e1 * inv; ws[WS_MIX + 2] = e2 * inv;
    for (int r = 0; r < 8; ++r){
      float v0 = q3_to_group[r*3+0], v1 = q3_to_group[r*3+1], v2 = q3_to_group[r*3+2];
      float mx = fmaxf(v0, fmaxf(v1, v2));
      float f0 = __expf(v0 - mx), f1 = __expf(v1 - mx), f2 = __expf(v2 - mx);
      float iv = 1.0f / (f0 + f1 + f2);
      ws[WS_M3 + r*3 + 0] = f0 * iv;
      ws[WS_M3 + r*3 + 1] = f1 * iv;
      ws[WS_M3 + r*3 + 2] = f2 * iv;
    }
  }
}

// ---------------- k1: main per-token kernel ----------------
// 256 blocks x 1024 threads (16 waves), min 4 waves/SIMD -> VGPR cap 128.
// W' staged in LDS; global loads in main loop are x only, prefetched 1 chunk.
__global__ __launch_bounds__(1024, 4) void k1_main(
    const float* __restrict__ x, const float* __restrict__ ws,
    float* __restrict__ gout, float* __restrict__ hout, float* __restrict__ part)
{
  __shared__ float sW[MROWS];
  __shared__ float lred[16][68];
  const int tid  = threadIdx.x;
  const int lane = tid & 63;
  const int wid  = tid >> 6;
  const int blk  = blockIdx.x;

  // stage merged W' into LDS
  for (int idx = tid * 4; idx < MROWS; idx += 4096)
    *(float4*)(sW + idx) = *(const float4*)(ws + WS_MERGED + idx);
  __syncthreads();

  const int tok0 = blk * TOK_PER_BLOCK + wid * 4;
  const int off0 = lane * 4;
  const float* xp0 = x + (size_t)tok0 * D + off0;
  const float* xp1 = xp0 + D;
  const float* xp2 = xp0 + 2 * D;
  const float* xp3 = xp0 + 3 * D;

  float sum[4] = {0,0,0,0}, sq[4] = {0,0,0,0};
  float t[NROW][4];
#pragma unroll
  for (int k = 0; k < NROW; ++k){ t[k][0]=t[k][1]=t[k][2]=t[k][3]=0.f; }

  float4 xc0 = *(const float4*)xp0;
  float4 xc1 = *(const float4*)xp1;
  float4 xc2 = *(const float4*)xp2;
  float4 xc3 = *(const float4*)xp3;

#pragma unroll 1
  for (int c = 0; c < 8; ++c){
    const int off = c * 256;
    float4 xn0, xn1, xn2, xn3;
    if (c < 7){
      xn0 = *(const float4*)(xp0 + off + 256);
      xn1 = *(const float4*)(xp1 + off + 256);
      xn2 = *(const float4*)(xp2 + off + 256);
      xn3 = *(const float4*)(xp3 + off + 256);
    }
    const float* wb = sW + off0 + off;

    // ---- G0: rows 0..2 + sum/sq ----
    {
      float4 w0 = *(const float4*)(wb + 0*D);
      float4 w1 = *(const float4*)(wb + 1*D);
      float4 w2 = *(const float4*)(wb + 2*D);
#pragma unroll
      for (int e = 0; e < 4; ++e){
        float x0 = ((const float*)&xc0)[e];
        float x1 = ((const float*)&xc1)[e];
        float x2 = ((const float*)&xc2)[e];
        float x3 = ((const float*)&xc3)[e];
        sum[0] += x0; sum[1] += x1; sum[2] += x2; sum[3] += x3;
        sq[0] = fmaf(x0,x0,sq[0]); sq[1] = fmaf(x1,x1,sq[1]);
        sq[2] = fmaf(x2,x2,sq[2]); sq[3] = fmaf(x3,x3,sq[3]);
        float w;
        w = ((const float*)&w0)[e]; t[0][0]=fmaf(x0,w,t[0][0]); t[0][1]=fmaf(x1,w,t[0][1]); t[0][2]=fmaf(x2,w,t[0][2]); t[0][3]=fmaf(x3,w,t[0][3]);
        w = ((const float*)&w1)[e]; t[1][0]=fmaf(x0,w,t[1][0]); t[1][1]=fmaf(x1,w,t[1][1]); t[1][2]=fmaf(x2,w,t[1][2]); t[1][3]=fmaf(x3,w,t[1][3]);
        w = ((const float*)&w2)[e]; t[2][0]=fmaf(x0,w,t[2][0]); t[2][1]=fmaf(x1,w,t[2][1]); t[2][2]=fmaf(x2,w,t[2][2]); t[2][3]=fmaf(x3,w,t[2][3]);
      }
    }
    // ---- G1: rows 3..5 ----
    {
      float4 w3 = *(const float4*)(wb + 3*D);
      float4 w4 = *(const float4*)(wb + 4*D);
      float4 w5 = *(const float4*)(wb + 5*D);
#pragma unroll
      for (int e = 0; e < 4; ++e){
        float x0 = ((const float*)&xc0)[e];
        float x1 = ((const float*)&xc1)[e];
        float x2 = ((const float*)&xc2)[e];
        float x3 = ((const float*)&xc3)[e];
        float w;
        w = ((const float*)&w3)[e]; t[3][0]=fmaf(x0,w,t[3][0]); t[3][1]=fmaf(x1,w,t[3][1]); t[3][2]=fmaf(x2,w,t[3][2]); t[3][3]=fmaf(x3,w,t[3][3]);
        w = ((const float*)&w4)[e]; t[4][0]=fmaf(x0,w,t[4][0]); t[4][1]=fmaf(x1,w,t[4][1]); t[4][2]=fmaf(x2,w,t[4][2]); t[4][3]=fmaf(x3,w,t[4][3]);
        w = ((const float*)&w5)[e]; t[5][0]=fmaf(x0,w,t[5][0]); t[5][1]=fmaf(x1,w,t[5][1]); t[5][2]=fmaf(x2,w,t[5][2]); t[5][3]=fmaf(x3,w,t[5][3]);
      }
    }
    // ---- G2: rows 6..8 ----
    {
      float4 w6 = *(const float4*)(wb + 6*D);
      float4 w7 = *(const float4*)(wb + 7*D);
      float4 w8 = *(const float4*)(wb + 8*D);
#pragma unroll
      for (int e = 0; e < 4; ++e){
        float x0 = ((const float*)&xc0)[e];
        float x1 = ((const float*)&xc1)[e];
        float x2 = ((const float*)&xc2)[e];
        float x3 = ((const float*)&xc3)[e];
        float w;
        w = ((const float*)&w6)[e]; t[6][0]=fmaf(x0,w,t[6][0]); t[6][1]=fmaf(x1,w,t[6][1]); t[6][2]=fmaf(x2,w,t[6][2]); t[6][3]=fmaf(x3,w,t[6][3]);
        w = ((const float*)&w7)[e]; t[7][0]=fmaf(x0,w,t[7][0]); t[7][1]=fmaf(x1,w,t[7][1]); t[7][2]=fmaf(x2,w,t[7][2]); t[7][3]=fmaf(x3,w,t[7][3]);
        w = ((const float*)&w8)[e]; t[8][0]=fmaf(x0,w,t[8][0]); t[8][1]=fmaf(x1,w,t[8][1]); t[8][2]=fmaf(x2,w,t[8][2]); t[8][3]=fmaf(x3,w,t[8][3]);
      }
    }
    // ---- G3: rows 9..10 ----
    {
      float4 w9 = *(const float4*)(wb + 9*D);
      float4 wA = *(const float4*)(wb + 10*D);
#pragma unroll
      for (int e = 0; e < 4; ++e){
        float x0 = ((const float*)&xc0)[e];
        float x1 = ((const float*)&xc1)[e];
        float x2 = ((const float*)&xc2)[e];
        float x3 = ((const float*)&xc3)[e];
        float w;
        w = ((const float*)&w9)[e]; t[9][0]=fmaf(x0,w,t[9][0]); t[9][1]=fmaf(x1,w,t[9][1]); t[9][2]=fmaf(x2,w,t[9][2]); t[9][3]=fmaf(x3,w,t[9][3]);
        w = ((const float*)&wA)[e]; t[10][0]=fmaf(x0,w,t[10][0]); t[10][1]=fmaf(x1,w,t[10][1]); t[10][2]=fmaf(x2,w,t[10][2]); t[10][3]=fmaf(x3,w,t[10][3]);
      }
    }
    if (c < 7){ xc0 = xn0; xc1 = xn1; xc2 = xn2; xc3 = xn3; }
  }

  // cross-lane reductions (broadcast totals to all lanes)
#pragma unroll
  for (int j = 0; j < 4; ++j){ sum[j] = wsum(sum[j]); sq[j] = wsum(sq[j]); }
#pragma unroll
  for (int k = 0; k < NROW; ++k){
#pragma unroll
    for (int j = 0; j < 4; ++j) t[k][j] = wsum(t[k][j]);
  }

  // constants
  float a[NROW], bb[NROW];
#pragma unroll
  for (int k = 0; k < NROW; ++k){ a[k] = ws[WS_A + k]; bb[k] = ws[WS_B + k]; }
  const float it    = ws[WS_IT];
  const float alpha = ws[WS_ALPHA];
  const float mix0 = ws[WS_MIX], mix1 = ws[WS_MIX+1], mix2 = ws[WS_MIX+2];
  float M3[8][3];
#pragma unroll
  for (int r = 0; r < 8; ++r){
#pragma unroll
    for (int g = 0; g < 3; ++g) M3[r][g] = ws[WS_M3 + r*3 + g];
  }

  // per-lane hexagram row: signs, fused (cos-anchor, wht) row
  float sgn[6];
#pragma unroll
  for (int j = 0; j < 6; ++j) sgn[j] = ((lane >> (5 - j)) & 1) ? 1.0f : -1.0f;
  const float C5 = 0.44721359549995793f; // 1/sqrt(5)
  const float A0[6] = { C5,  C5,  C5,  C5,  C5, 0.f };
  const float A1[6] = {-0.5f, 0.5f, -0.5f, 0.f, 0.f, 0.5f};
  const float A2[6] = {-C5, -C5, 0.f, -C5, -C5, -C5};
  float cs0 = 0.f, cs1 = 0.f, cs2 = 0.f;
#pragma unroll
  for (int j = 0; j < 6; ++j){
    cs0 = fmaf(sgn[j], A0[j], cs0);
    cs1 = fmaf(sgn[j], A1[j], cs1);
    cs2 = fmaf(sgn[j], A2[j], cs2);
  }
  const int pc = __popc(lane);
  const float w7c = 1.0f / 7.0f;
  float wh0 = (pc >= 5) ? w7c  : 0.f;
  float wh1 = (pc == 3) ? 0.05f: 0.f;
  float wh2 = (pc <= 1) ? w7c  : 0.f;
  float m60 = (1.f - alpha)*cs0 + alpha*wh0;
  float m61 = (1.f - alpha)*cs1 + alpha*wh1;
  float m62 = (1.f - alpha)*cs2 + alpha*wh2;

  float hsum = 0.f, ga0 = 0.f, ga1 = 0.f, ga2 = 0.f;

#pragma unroll
  for (int j = 0; j < 4; ++j){
    const int tok = tok0 + j;
    float mean = sum[j] * (1.0f / D);
    float var  = fmaf(sq[j], 1.0f / D, -mean * mean);
    float rr   = rsqrtf(var + 1e-5f);
    float u[NROW];
#pragma unroll
    for (int k = 0; k < NROW; ++k){
      float d = fmaf(-mean, a[k], t[k][j]);
      u[k] = tanh_fast(fmaf(rr, d, bb[k]));
    }

    // ---- Q2 ----
    float p01 = u[0] + u[1], m01 = u[0] - u[1];
    float l0 = -p01*it, l1 = -m01*it, l2 = m01*it, l3 = p01*it;
    float mx2 = fmaxf(fmaxf(l0, l1), fmaxf(l2, l3));
    float e0 = __expf(l0-mx2), e1 = __expf(l1-mx2), e2 = __expf(l2-mx2), e3 = __expf(l3-mx2);
    float i2 = rcp_fast(e0 + e1 + e2 + e3);
    float s2g0 = e3 * i2, s2g1 = (e1 + e2) * i2, s2g2 = e0 * i2;

    // ---- Q3 ----
    float l3v[8]; float mx3 = -1e30f;
#pragma unroll
    for (int v = 0; v < 8; ++v){
      float acc = ((v & 4) ? u[2] : -u[2]) + ((v & 2) ? u[3] : -u[3]) + ((v & 1) ? u[4] : -u[4]);
      l3v[v] = acc * it;
      mx3 = fmaxf(mx3, l3v[v]);
    }
    float w3v[8]; float se3 = 0.f;
#pragma unroll
    for (int v = 0; v < 8; ++v){ w3v[v] = __expf(l3v[v] - mx3); se3 += w3v[v]; }
    float i3 = rcp_fast(se3);
    float s3g0 = 0.f, s3g1 = 0.f, s3g2 = 0.f;
#pragma unroll
    for (int v = 0; v < 8; ++v){
      s3g0 = fmaf(w3v[v], M3[v][0], s3g0);
      s3g1 = fmaf(w3v[v], M3[v][1], s3g1);
      s3g2 = fmaf(w3v[v], M3[v][2], s3g2);
    }
    s3g0 *= i3; s3g1 *= i3; s3g2 *= i3;

    // ---- Q6 (lane-parallel over 64 vertices) ----
    float lg = 0.f;
#pragma unroll
    for (int jj = 0; jj < 6; ++jj) lg = fmaf(sgn[jj], u[5 + jj], lg);
    lg *= it;
    float mx6 = wmax(lg);
    float p   = __expf(lg - mx6);
    float se6 = wsum(p);
    float hw  = p * rcp_fast(se6);
    hout[(size_t)tok * 64 + lane] = hw;
    hsum += hw;
    float s6g0 = wsum(hw * m60);
    float s6g1 = wsum(hw * m61);
    float s6g2 = wsum(hw * m62);

    // ---- combine + group softmax ----
    float g0 = mix0*s2g0 + mix1*s3g0 + mix2*s6g0;
    float g1 = mix0*s2g1 + mix1*s3g1 + mix2*s6g1;
    float g2 = mix0*s2g2 + mix1*s3g2 + mix2*s6g2;
    float gm = fmaxf(g0, fmaxf(g1, g2));
    float y0 = __expf(g0-gm), y1 = __expf(g1-gm), y2 = __expf(g2-gm);
    float gi = rcp_fast(y0 + y1 + y2);
    float gw0 = y0*gi, gw1 = y1*gi, gw2 = y2*gi;
    ga0 += gw0; ga1 += gw1; ga2 += gw2;
    if (lane < 3){
      float val = (lane == 0) ? gw0 : (lane == 1) ? gw1 : gw2;
      gout[(size_t)tok * 3 + lane] = val;
    }
  }

  // block partials for lb_loss
  lred[wid][lane] = hsum;
  if (lane < 3){
    float val = (lane == 0) ? ga0 : (lane == 1) ? ga1 : ga2;
    lred[wid][64 + lane] = val;
  }
  __syncthreads();
  if (tid < 67){
    float v = 0.f;
#pragma unroll
    for (int r = 0; r < 16; ++r) v += lred[r][tid];
    part[tid * K1_BLOCKS + blk] = v;
  }
}

// ---------------- k2: final reduction + lb_loss ----------------
__global__ __launch_bounds__(256) void k2_loss(const float* __restrict__ part,
                                               float* __restrict__ lout)
{
  __shared__ float sums[68];
  const int tid = threadIdx.x;
  const int lane = tid & 63;
  const int wid  = tid >> 6;
  for (int jv = wid; jv < 67; jv += 4){
    const float* p = part + jv * K1_BLOCKS;
    float v = p[lane] + p[lane + 64] + p[lane + 128] + p[lane + 192];
    v = wsum(v);
    if (lane == 0) sums[jv] = v;
  }
  __syncthreads();
  if (wid == 0){
    const float inv = 1.0f / (float)NTOK;
    float mh = sums[lane] * inv;
    float term = 0.1f * mh * logf(mh + 1e-8f);
    if (lane < 3){
      float mg = sums[64 + lane] * inv;
      term += mg * logf(mg + 1e-8f);
    }
    float L = wsum(term);
    if (lane == 0) lout[0] = L;
  }
}

extern "C" void kernel_launch(void* const* d_in, const int* in_sizes, int n_in,
                              void* d_out, int out_size, void* d_ws, size_t ws_size,
                              hipStream_t stream)
{
  const float* x             = (const float*)d_in[0];
  const float* ln_w          = (const float*)d_in[1];
  const float* ln_b          = (const float*)d_in[2];
  const float* w_q2          = (const float*)d_in[3];
  const float* w_q3          = (const float*)d_in[4];
  const float* w_q6          = (const float*)d_in[5];
  const float* log_temp      = (const float*)d_in[6];
  const float* log_scale_mix = (const float*)d_in[7];
  const float* q3_to_group   = (const float*)d_in[8];
  const float* log_wht_mix   = (const float*)d_in[9];

  float* out  = (float*)d_out;
  float* gout = out;                                        // (B,T,3)
  float* hout = out + (size_t)NTOK * 3;                     // (B,T,64)
  float* lout = out + (size_t)NTOK * 3 + (size_t)NTOK * 64; // scalar
  float* ws   = (float*)d_ws;

  k0_prep<<<12, 256, 0, stream>>>(ln_w, ln_b, w_q2, w_q3, w_q6,
                                  log_temp, log_scale_mix, q3_to_group, log_wht_mix, ws);
  k1_main<<<K1_BLOCKS, 1024, 0, stream>>>(x, ws, gout, hout, ws + WS_PART);
  k2_loss<<<1, 256, 0, stream>>>(ws + WS_PART, lout);
}

// Round 4
// 87.837 us; speedup vs baseline: 1.2388x; 1.0055x over previous
//
#include <hip/hip_runtime.h>
#include <math.h>

#define D 2048
#define NTOK 16384
#define NROW 11
#define MROWS (NROW * D)          // 22528 floats = 88 KB
#define K1_BLOCKS 256
#define TOK_PER_BLOCK 64

// ws float layout:
// [0..10] a_k   [16..26] b_k   [32] inv_temp  [33] alpha  [34..36] mix
// [40..63] M3 (8x3)  [64 .. 64+22528) merged W'  [WS_PART ..) partials [67][256]
#define WS_A 0
#define WS_B 16
#define WS_IT 32
#define WS_ALPHA 33
#define WS_MIX 34
#define WS_M3 40
#define WS_MERGED 64
#define WS_PART (WS_MERGED + MROWS)

__device__ __forceinline__ float wsum(float v){
#pragma unroll
  for (int m = 1; m < 64; m <<= 1) v += __shfl_xor(v, m, 64);
  return v;
}
__device__ __forceinline__ float wmax(float v){
#pragma unroll
  for (int m = 1; m < 64; m <<= 1) v = fmaxf(v, __shfl_xor(v, m, 64));
  return v;
}
__device__ __forceinline__ float rcp_fast(float x){ return __builtin_amdgcn_rcpf(x); }
__device__ __forceinline__ float tanh_fast(float x){
  float e = __expf(2.0f * x);
  return 1.0f - 2.0f * rcp_fast(e + 1.0f);
}

// ---------------- k0: merge rows + constants (12 blocks) ----------------
__global__ __launch_bounds__(256) void k0_prep(
    const float* __restrict__ ln_w, const float* __restrict__ ln_b,
    const float* __restrict__ w_q2, const float* __restrict__ w_q3,
    const float* __restrict__ w_q6,
    const float* __restrict__ log_temp, const float* __restrict__ log_scale_mix,
    const float* __restrict__ q3_to_group, const float* __restrict__ log_wht_mix,
    float* __restrict__ ws)
{
  const int tid = threadIdx.x;
  const int k = blockIdx.x;
  if (k < NROW){
    const float* row = (k < 2) ? (w_q2 + (size_t)k * D)
                     : (k < 5) ? (w_q3 + (size_t)(k - 2) * D)
                               : (w_q6 + (size_t)(k - 5) * D);
    float pa = 0.f, pb = 0.f;
    for (int i = tid; i < D; i += 256){
      float w = row[i];
      float m = ln_w[i] * w;
      ws[WS_MERGED + k * D + i] = m;
      pa += m;                       // a_k = sum(ln_w * w)
      pb = fmaf(ln_b[i], w, pb);     // b_k = sum(ln_b * w)
    }
    __shared__ float red[8];
    pa = wsum(pa); pb = wsum(pb);
    if ((tid & 63) == 0){ red[tid >> 6] = pa; red[4 + (tid >> 6)] = pb; }
    __syncthreads();
    if (tid == 0){
      ws[WS_A + k] = red[0] + red[1] + red[2] + red[3];
      ws[WS_B + k] = red[4] + red[5] + red[6] + red[7];
    }
  } else if (tid == 0){
    float t = __expf(log_temp[0]);
    t = fminf(fmaxf(t, 0.1f), 5.0f);
    ws[WS_IT] = 1.0f / t;
    ws[WS_ALPHA] = 1.0f / (1.0f + __expf(-log_wht_mix[0]));
    float m0 = log_scale_mix[0], m1 = log_scale_mix[1], m2 = log_scale_mix[2];
    float mm = fmaxf(m0, fmaxf(m1, m2));
    float e0 = __expf(m0 - mm), e1 = __expf(m1 - mm), e2 = __expf(m2 - mm);
    float inv = 1.0f / (e0 + e1 + e2);
    ws[WS_MIX + 0] = e0 * inv; ws[WS_MIX + 1] = e1 * inv; ws[WS_MIX + 2] = e2 * inv;
    for (int r = 0; r < 8; ++r){
      float v0 = q3_to_group[r*3+0], v1 = q3_to_group[r*3+1], v2 = q3_to_group[r*3+2];
      float mx = fmaxf(v0, fmaxf(v1, v2));
      float f0 = __expf(v0 - mx), f1 = __expf(v1 - mx), f2 = __expf(v2 - mx);
      float iv = 1.0f / (f0 + f1 + f2);
      ws[WS_M3 + r*3 + 0] = f0 * iv;
      ws[WS_M3 + r*3 + 1] = f1 * iv;
      ws[WS_M3 + r*3 + 2] = f2 * iv;
    }
  }
}

// ---------------- k1: main per-token kernel ----------------
// 256 blocks x 1024 threads (16 waves). LDS caps residency at 1 block/CU =
// exactly 4 waves/EU, so pin waves_per_eu to (4,4) -> firm 128-VGPR budget,
// eliminating the 8-wave/EU default that forced VGPR=64 + scratch spills.
__global__
__attribute__((amdgpu_flat_work_group_size(1024, 1024), amdgpu_waves_per_eu(4, 4)))
void k1_main(
    const float* __restrict__ x, const float* __restrict__ ws,
    float* __restrict__ gout, float* __restrict__ hout, float* __restrict__ part)
{
  __shared__ float sW[MROWS];
  __shared__ float lred[16][68];
  const int tid  = threadIdx.x;
  const int lane = tid & 63;
  const int wid  = tid >> 6;
  const int blk  = blockIdx.x;

  // stage merged W' into LDS
  for (int idx = tid * 4; idx < MROWS; idx += 4096)
    *(float4*)(sW + idx) = *(const float4*)(ws + WS_MERGED + idx);
  __syncthreads();

  const int tok0 = blk * TOK_PER_BLOCK + wid * 4;
  const int off0 = lane * 4;
  const float* xp0 = x + (size_t)tok0 * D + off0;
  const float* xp1 = xp0 + D;
  const float* xp2 = xp0 + 2 * D;
  const float* xp3 = xp0 + 3 * D;

  float sum[4] = {0,0,0,0}, sq[4] = {0,0,0,0};
  float t[NROW][4];
#pragma unroll
  for (int k = 0; k < NROW; ++k){ t[k][0]=t[k][1]=t[k][2]=t[k][3]=0.f; }

  float4 xc0 = *(const float4*)xp0;
  float4 xc1 = *(const float4*)xp1;
  float4 xc2 = *(const float4*)xp2;
  float4 xc3 = *(const float4*)xp3;

#pragma unroll 1
  for (int c = 0; c < 8; ++c){
    const int off = c * 256;
    float4 xn0, xn1, xn2, xn3;
    if (c < 7){
      xn0 = *(const float4*)(xp0 + off + 256);
      xn1 = *(const float4*)(xp1 + off + 256);
      xn2 = *(const float4*)(xp2 + off + 256);
      xn3 = *(const float4*)(xp3 + off + 256);
    }
    const float* wb = sW + off0 + off;

    // ---- G0: rows 0..2 + sum/sq ----
    {
      float4 w0 = *(const float4*)(wb + 0*D);
      float4 w1 = *(const float4*)(wb + 1*D);
      float4 w2 = *(const float4*)(wb + 2*D);
#pragma unroll
      for (int e = 0; e < 4; ++e){
        float x0 = ((const float*)&xc0)[e];
        float x1 = ((const float*)&xc1)[e];
        float x2 = ((const float*)&xc2)[e];
        float x3 = ((const float*)&xc3)[e];
        sum[0] += x0; sum[1] += x1; sum[2] += x2; sum[3] += x3;
        sq[0] = fmaf(x0,x0,sq[0]); sq[1] = fmaf(x1,x1,sq[1]);
        sq[2] = fmaf(x2,x2,sq[2]); sq[3] = fmaf(x3,x3,sq[3]);
        float w;
        w = ((const float*)&w0)[e]; t[0][0]=fmaf(x0,w,t[0][0]); t[0][1]=fmaf(x1,w,t[0][1]); t[0][2]=fmaf(x2,w,t[0][2]); t[0][3]=fmaf(x3,w,t[0][3]);
        w = ((const float*)&w1)[e]; t[1][0]=fmaf(x0,w,t[1][0]); t[1][1]=fmaf(x1,w,t[1][1]); t[1][2]=fmaf(x2,w,t[1][2]); t[1][3]=fmaf(x3,w,t[1][3]);
        w = ((const float*)&w2)[e]; t[2][0]=fmaf(x0,w,t[2][0]); t[2][1]=fmaf(x1,w,t[2][1]); t[2][2]=fmaf(x2,w,t[2][2]); t[2][3]=fmaf(x3,w,t[2][3]);
      }
    }
    // ---- G1: rows 3..5 ----
    {
      float4 w3 = *(const float4*)(wb + 3*D);
      float4 w4 = *(const float4*)(wb + 4*D);
      float4 w5 = *(const float4*)(wb + 5*D);
#pragma unroll
      for (int e = 0; e < 4; ++e){
        float x0 = ((const float*)&xc0)[e];
        float x1 = ((const float*)&xc1)[e];
        float x2 = ((const float*)&xc2)[e];
        float x3 = ((const float*)&xc3)[e];
        float w;
        w = ((const float*)&w3)[e]; t[3][0]=fmaf(x0,w,t[3][0]); t[3][1]=fmaf(x1,w,t[3][1]); t[3][2]=fmaf(x2,w,t[3][2]); t[3][3]=fmaf(x3,w,t[3][3]);
        w = ((const float*)&w4)[e]; t[4][0]=fmaf(x0,w,t[4][0]); t[4][1]=fmaf(x1,w,t[4][1]); t[4][2]=fmaf(x2,w,t[4][2]); t[4][3]=fmaf(x3,w,t[4][3]);
        w = ((const float*)&w5)[e]; t[5][0]=fmaf(x0,w,t[5][0]); t[5][1]=fmaf(x1,w,t[5][1]); t[5][2]=fmaf(x2,w,t[5][2]); t[5][3]=fmaf(x3,w,t[5][3]);
      }
    }
    // ---- G2: rows 6..8 ----
    {
      float4 w6 = *(const float4*)(wb + 6*D);
      float4 w7 = *(const float4*)(wb + 7*D);
      float4 w8 = *(const float4*)(wb + 8*D);
#pragma unroll
      for (int e = 0; e < 4; ++e){
        float x0 = ((const float*)&xc0)[e];
        float x1 = ((const float*)&xc1)[e];
        float x2 = ((const float*)&xc2)[e];
        float x3 = ((const float*)&xc3)[e];
        float w;
        w = ((const float*)&w6)[e]; t[6][0]=fmaf(x0,w,t[6][0]); t[6][1]=fmaf(x1,w,t[6][1]); t[6][2]=fmaf(x2,w,t[6][2]); t[6][3]=fmaf(x3,w,t[6][3]);
        w = ((const float*)&w7)[e]; t[7][0]=fmaf(x0,w,t[7][0]); t[7][1]=fmaf(x1,w,t[7][1]); t[7][2]=fmaf(x2,w,t[7][2]); t[7][3]=fmaf(x3,w,t[7][3]);
        w = ((const float*)&w8)[e]; t[8][0]=fmaf(x0,w,t[8][0]); t[8][1]=fmaf(x1,w,t[8][1]); t[8][2]=fmaf(x2,w,t[8][2]); t[8][3]=fmaf(x3,w,t[8][3]);
      }
    }
    // ---- G3: rows 9..10 ----
    {
      float4 w9 = *(const float4*)(wb + 9*D);
      float4 wA = *(const float4*)(wb + 10*D);
#pragma unroll
      for (int e = 0; e < 4; ++e){
        float x0 = ((const float*)&xc0)[e];
        float x1 = ((const float*)&xc1)[e];
        float x2 = ((const float*)&xc2)[e];
        float x3 = ((const float*)&xc3)[e];
        float w;
        w = ((const float*)&w9)[e]; t[9][0]=fmaf(x0,w,t[9][0]); t[9][1]=fmaf(x1,w,t[9][1]); t[9][2]=fmaf(x2,w,t[9][2]); t[9][3]=fmaf(x3,w,t[9][3]);
        w = ((const float*)&wA)[e]; t[10][0]=fmaf(x0,w,t[10][0]); t[10][1]=fmaf(x1,w,t[10][1]); t[10][2]=fmaf(x2,w,t[10][2]); t[10][3]=fmaf(x3,w,t[10][3]);
      }
    }
    if (c < 7){ xc0 = xn0; xc1 = xn1; xc2 = xn2; xc3 = xn3; }
  }

  // cross-lane reductions (broadcast totals to all lanes)
#pragma unroll
  for (int j = 0; j < 4; ++j){ sum[j] = wsum(sum[j]); sq[j] = wsum(sq[j]); }
#pragma unroll
  for (int k = 0; k < NROW; ++k){
#pragma unroll
    for (int j = 0; j < 4; ++j) t[k][j] = wsum(t[k][j]);
  }

  // constants
  float a[NROW], bb[NROW];
#pragma unroll
  for (int k = 0; k < NROW; ++k){ a[k] = ws[WS_A + k]; bb[k] = ws[WS_B + k]; }
  const float it    = ws[WS_IT];
  const float alpha = ws[WS_ALPHA];
  const float mix0 = ws[WS_MIX], mix1 = ws[WS_MIX+1], mix2 = ws[WS_MIX+2];
  float M3[8][3];
#pragma unroll
  for (int r = 0; r < 8; ++r){
#pragma unroll
    for (int g = 0; g < 3; ++g) M3[r][g] = ws[WS_M3 + r*3 + g];
  }

  // per-lane hexagram row: signs, fused (cos-anchor, wht) row
  float sgn[6];
#pragma unroll
  for (int j = 0; j < 6; ++j) sgn[j] = ((lane >> (5 - j)) & 1) ? 1.0f : -1.0f;
  const float C5 = 0.44721359549995793f; // 1/sqrt(5)
  const float A0[6] = { C5,  C5,  C5,  C5,  C5, 0.f };
  const float A1[6] = {-0.5f, 0.5f, -0.5f, 0.f, 0.f, 0.5f};
  const float A2[6] = {-C5, -C5, 0.f, -C5, -C5, -C5};
  float cs0 = 0.f, cs1 = 0.f, cs2 = 0.f;
#pragma unroll
  for (int j = 0; j < 6; ++j){
    cs0 = fmaf(sgn[j], A0[j], cs0);
    cs1 = fmaf(sgn[j], A1[j], cs1);
    cs2 = fmaf(sgn[j], A2[j], cs2);
  }
  const int pc = __popc(lane);
  const float w7c = 1.0f / 7.0f;
  float wh0 = (pc >= 5) ? w7c  : 0.f;
  float wh1 = (pc == 3) ? 0.05f: 0.f;
  float wh2 = (pc <= 1) ? w7c  : 0.f;
  float m60 = (1.f - alpha)*cs0 + alpha*wh0;
  float m61 = (1.f - alpha)*cs1 + alpha*wh1;
  float m62 = (1.f - alpha)*cs2 + alpha*wh2;

  float hsum = 0.f, ga0 = 0.f, ga1 = 0.f, ga2 = 0.f;

#pragma unroll
  for (int j = 0; j < 4; ++j){
    const int tok = tok0 + j;
    float mean = sum[j] * (1.0f / D);
    float var  = fmaf(sq[j], 1.0f / D, -mean * mean);
    float rr   = rsqrtf(var + 1e-5f);
    float u[NROW];
#pragma unroll
    for (int k = 0; k < NROW; ++k){
      float d = fmaf(-mean, a[k], t[k][j]);
      u[k] = tanh_fast(fmaf(rr, d, bb[k]));
    }

    // ---- Q2 ----
    float p01 = u[0] + u[1], m01 = u[0] - u[1];
    float l0 = -p01*it, l1 = -m01*it, l2 = m01*it, l3 = p01*it;
    float mx2 = fmaxf(fmaxf(l0, l1), fmaxf(l2, l3));
    float e0 = __expf(l0-mx2), e1 = __expf(l1-mx2), e2 = __expf(l2-mx2), e3 = __expf(l3-mx2);
    float i2 = rcp_fast(e0 + e1 + e2 + e3);
    float s2g0 = e3 * i2, s2g1 = (e1 + e2) * i2, s2g2 = e0 * i2;

    // ---- Q3 ----
    float l3v[8]; float mx3 = -1e30f;
#pragma unroll
    for (int v = 0; v < 8; ++v){
      float acc = ((v & 4) ? u[2] : -u[2]) + ((v & 2) ? u[3] : -u[3]) + ((v & 1) ? u[4] : -u[4]);
      l3v[v] = acc * it;
      mx3 = fmaxf(mx3, l3v[v]);
    }
    float w3v[8]; float se3 = 0.f;
#pragma unroll
    for (int v = 0; v < 8; ++v){ w3v[v] = __expf(l3v[v] - mx3); se3 += w3v[v]; }
    float i3 = rcp_fast(se3);
    float s3g0 = 0.f, s3g1 = 0.f, s3g2 = 0.f;
#pragma unroll
    for (int v = 0; v < 8; ++v){
      s3g0 = fmaf(w3v[v], M3[v][0], s3g0);
      s3g1 = fmaf(w3v[v], M3[v][1], s3g1);
      s3g2 = fmaf(w3v[v], M3[v][2], s3g2);
    }
    s3g0 *= i3; s3g1 *= i3; s3g2 *= i3;

    // ---- Q6 (lane-parallel over 64 vertices) ----
    float lg = 0.f;
#pragma unroll
    for (int jj = 0; jj < 6; ++jj) lg = fmaf(sgn[jj], u[5 + jj], lg);
    lg *= it;
    float mx6 = wmax(lg);
    float p   = __expf(lg - mx6);
    float se6 = wsum(p);
    float hw  = p * rcp_fast(se6);
    hout[(size_t)tok * 64 + lane] = hw;
    hsum += hw;
    float s6g0 = wsum(hw * m60);
    float s6g1 = wsum(hw * m61);
    float s6g2 = wsum(hw * m62);

    // ---- combine + group softmax ----
    float g0 = mix0*s2g0 + mix1*s3g0 + mix2*s6g0;
    float g1 = mix0*s2g1 + mix1*s3g1 + mix2*s6g1;
    float g2 = mix0*s2g2 + mix1*s3g2 + mix2*s6g2;
    float gm = fmaxf(g0, fmaxf(g1, g2));
    float y0 = __expf(g0-gm), y1 = __expf(g1-gm), y2 = __expf(g2-gm);
    float gi = rcp_fast(y0 + y1 + y2);
    float gw0 = y0*gi, gw1 = y1*gi, gw2 = y2*gi;
    ga0 += gw0; ga1 += gw1; ga2 += gw2;
    if (lane < 3){
      float val = (lane == 0) ? gw0 : (lane == 1) ? gw1 : gw2;
      gout[(size_t)tok * 3 + lane] = val;
    }
  }

  // block partials for lb_loss
  lred[wid][lane] = hsum;
  if (lane < 3){
    float val = (lane == 0) ? ga0 : (lane == 1) ? ga1 : ga2;
    lred[wid][64 + lane] = val;
  }
  __syncthreads();
  if (tid < 67){
    float v = 0.f;
#pragma unroll
    for (int r = 0; r < 16; ++r) v += lred[r][tid];
    part[tid * K1_BLOCKS + blk] = v;
  }
}

// ---------------- k2: final reduction + lb_loss ----------------
__global__ __launch_bounds__(256) void k2_loss(const float* __restrict__ part,
                                               float* __restrict__ lout)
{
  __shared__ float sums[68];
  const int tid = threadIdx.x;
  const int lane = tid & 63;
  const int wid  = tid >> 6;
  for (int jv = wid; jv < 67; jv += 4){
    const float* p = part + jv * K1_BLOCKS;
    float v = p[lane] + p[lane + 64] + p[lane + 128] + p[lane + 192];
    v = wsum(v);
    if (lane == 0) sums[jv] = v;
  }
  __syncthreads();
  if (wid == 0){
    const float inv = 1.0f / (float)NTOK;
    float mh = sums[lane] * inv;
    float term = 0.1f * mh * logf(mh + 1e-8f);
    if (lane < 3){
      float mg = sums[64 + lane] * inv;
      term += mg * logf(mg + 1e-8f);
    }
    float L = wsum(term);
    if (lane == 0) lout[0] = L;
  }
}

extern "C" void kernel_launch(void* const* d_in, const int* in_sizes, int n_in,
                              void* d_out, int out_size, void* d_ws, size_t ws_size,
                              hipStream_t stream)
{
  const float* x             = (const float*)d_in[0];
  const float* ln_w          = (const float*)d_in[1];
  const float* ln_b          = (const float*)d_in[2];
  const float* w_q2          = (const float*)d_in[3];
  const float* w_q3          = (const float*)d_in[4];
  const float* w_q6          = (const float*)d_in[5];
  const float* log_temp      = (const float*)d_in[6];
  const float* log_scale_mix = (const float*)d_in[7];
  const float* q3_to_group   = (const float*)d_in[8];
  const float* log_wht_mix   = (const float*)d_in[9];

  float* out  = (float*)d_out;
  float* gout = out;                                        // (B,T,3)
  float* hout = out + (size_t)NTOK * 3;                     // (B,T,64)
  float* lout = out + (size_t)NTOK * 3 + (size_t)NTOK * 64; // scalar
  float* ws   = (float*)d_ws;

  k0_prep<<<12, 256, 0, stream>>>(ln_w, ln_b, w_q2, w_q3, w_q6,
                                  log_temp, log_scale_mix, q3_to_group, log_wht_mix, ws);
  k1_main<<<K1_BLOCKS, 1024, 0, stream>>>(x, ws, gout, hout, ws + WS_PART);
  k2_loss<<<1, 256, 0, stream>>>(ws + WS_PART, lout);
}

// Round 5
// 74.383 us; speedup vs baseline: 1.4628x; 1.1809x over previous
//
#include <hip/hip_runtime.h>
#include <math.h>

#define D 2048
#define NTOK 16384
#define NROW 11
#define MROWS_U32 (NROW * D / 2)   // 11264 uints = 44 KB (packed 2xbf16)
#define K1_BLOCKS 512
#define TOK_PER_BLOCK 32

// ws layout (4-byte units):
// [0..10] a_k   [16..26] b_k   [32] inv_temp  [33] alpha  [34..36] mix
// [40..63] M3 (8x3)  [64 .. 64+11264) packed-bf16 W'  [WS_PART ..) partials [67][512]
#define WS_A 0
#define WS_B 16
#define WS_IT 32
#define WS_ALPHA 33
#define WS_MIX 34
#define WS_M3 40
#define WS_MERGED 64
#define WS_PART (WS_MERGED + MROWS_U32)

__device__ __forceinline__ float wsum(float v){
#pragma unroll
  for (int m = 1; m < 64; m <<= 1) v += __shfl_xor(v, m, 64);
  return v;
}
__device__ __forceinline__ float wmax(float v){
#pragma unroll
  for (int m = 1; m < 64; m <<= 1) v = fmaxf(v, __shfl_xor(v, m, 64));
  return v;
}
__device__ __forceinline__ float rcp_fast(float x){ return __builtin_amdgcn_rcpf(x); }
__device__ __forceinline__ float tanh_fast(float x){
  float e = __expf(2.0f * x);
  return 1.0f - 2.0f * rcp_fast(e + 1.0f);
}
// round-to-nearest-even f32 -> bf16 (upper 16 bits)
__device__ __forceinline__ unsigned int bf16_rne(float f){
  unsigned int u = __float_as_uint(f);
  return (u + 0x7fffu + ((u >> 16) & 1u)) >> 16;
}
__device__ __forceinline__ void bf2_unpack(unsigned int u, float &a, float &b){
  a = __uint_as_float(u << 16);          // low half  = even element
  b = __uint_as_float(u & 0xffff0000u);  // high half = odd element
}

// ---------------- k0: merge rows (bf16-packed) + constants (12 blocks) ----------------
__global__ __launch_bounds__(256) void k0_prep(
    const float* __restrict__ ln_w, const float* __restrict__ ln_b,
    const float* __restrict__ w_q2, const float* __restrict__ w_q3,
    const float* __restrict__ w_q6,
    const float* __restrict__ log_temp, const float* __restrict__ log_scale_mix,
    const float* __restrict__ q3_to_group, const float* __restrict__ log_wht_mix,
    float* __restrict__ ws)
{
  const int tid = threadIdx.x;
  const int k = blockIdx.x;
  unsigned int* wsu = (unsigned int*)ws;
  if (k < NROW){
    const float* row = (k < 2) ? (w_q2 + (size_t)k * D)
                     : (k < 5) ? (w_q3 + (size_t)(k - 2) * D)
                               : (w_q6 + (size_t)(k - 5) * D);
    float pa = 0.f, pb = 0.f;
    for (int i = tid * 2; i < D; i += 512){
      float w0 = row[i], w1 = row[i + 1];
      unsigned int b0 = bf16_rne(ln_w[i] * w0);
      unsigned int b1 = bf16_rne(ln_w[i + 1] * w1);
      // accumulate a_k from the ROUNDED values (consistency with k1's dot)
      pa += __uint_as_float(b0 << 16) + __uint_as_float(b1 << 16);
      pb = fmaf(ln_b[i], w0, pb);
      pb = fmaf(ln_b[i + 1], w1, pb);
      wsu[WS_MERGED + k * 1024 + i / 2] = (b1 << 16) | b0;
    }
    __shared__ float red[8];
    pa = wsum(pa); pb = wsum(pb);
    if ((tid & 63) == 0){ red[tid >> 6] = pa; red[4 + (tid >> 6)] = pb; }
    __syncthreads();
    if (tid == 0){
      ws[WS_A + k] = red[0] + red[1] + red[2] + red[3];
      ws[WS_B + k] = red[4] + red[5] + red[6] + red[7];
    }
  } else if (tid == 0){
    float t = __expf(log_temp[0]);
    t = fminf(fmaxf(t, 0.1f), 5.0f);
    ws[WS_IT] = 1.0f / t;
    ws[WS_ALPHA] = 1.0f / (1.0f + __expf(-log_wht_mix[0]));
    float m0 = log_scale_mix[0], m1 = log_scale_mix[1], m2 = log_scale_mix[2];
    float mm = fmaxf(m0, fmaxf(m1, m2));
    float e0 = __expf(m0 - mm), e1 = __expf(m1 - mm), e2 = __expf(m2 - mm);
    float inv = 1.0f / (e0 + e1 + e2);
    ws[WS_MIX + 0] = e0 * inv; ws[WS_MIX + 1] = e1 * inv; ws[WS_MIX + 2] = e2 * inv;
    for (int r = 0; r < 8; ++r){
      float v0 = q3_to_group[r*3+0], v1 = q3_to_group[r*3+1], v2 = q3_to_group[r*3+2];
      float mx = fmaxf(v0, fmaxf(v1, v2));
      float f0 = __expf(v0 - mx), f1 = __expf(v1 - mx), f2 = __expf(v2 - mx);
      float iv = 1.0f / (f0 + f1 + f2);
      ws[WS_M3 + r*3 + 0] = f0 * iv;
      ws[WS_M3 + r*3 + 1] = f1 * iv;
      ws[WS_M3 + r*3 + 2] = f2 * iv;
    }
  }
}

// ---------------- k1: main per-token kernel ----------------
// 512 blocks x 1024 threads (16 waves). 2 tokens/wave. W' packed bf16 in LDS
// (44 KB -> 2 blocks/CU). Live set sized to fit the 64-VGPR budget the
// backend pins for 1024-thread workgroups: t[22]+ss[4]+xc[8]+transients.
__global__ __launch_bounds__(1024) void k1_main(
    const float* __restrict__ x, const float* __restrict__ ws,
    float* __restrict__ gout, float* __restrict__ hout, float* __restrict__ part)
{
  __shared__ unsigned int sW[MROWS_U32];
  __shared__ float lred[16][68];
  const int tid  = threadIdx.x;
  const int lane = tid & 63;
  const int wid  = tid >> 6;
  const int blk  = blockIdx.x;

  // stage packed W' into LDS (uint4, 2816 vecs, 1024 threads -> 3 iters)
  {
    const uint4* src = (const uint4*)((const unsigned int*)ws + WS_MERGED);
    uint4* dst = (uint4*)sW;
    for (int idx = tid; idx < MROWS_U32 / 4; idx += 1024) dst[idx] = src[idx];
  }
  __syncthreads();

  const int tok0 = blk * TOK_PER_BLOCK + wid * 2;
  const int off0 = lane * 4;
  const float* xp0 = x + (size_t)tok0 * D + off0;
  const float* xp1 = xp0 + D;

  float sum0 = 0.f, sum1 = 0.f, sq0 = 0.f, sq1 = 0.f;
  float t[NROW][2];
#pragma unroll
  for (int k = 0; k < NROW; ++k){ t[k][0] = 0.f; t[k][1] = 0.f; }

#pragma unroll 1
  for (int c = 0; c < 8; ++c){
    const int off = c * 256;
    float4 xv0 = *(const float4*)(xp0 + off);
    float4 xv1 = *(const float4*)(xp1 + off);
    const unsigned int* wb = sW + c * 128 + lane * 2;

    float x00 = xv0.x, x01 = xv0.y, x02 = xv0.z, x03 = xv0.w;
    float x10 = xv1.x, x11 = xv1.y, x12 = xv1.z, x13 = xv1.w;
    sum0 += (x00 + x01) + (x02 + x03);
    sum1 += (x10 + x11) + (x12 + x13);
    sq0 = fmaf(x00,x00, fmaf(x01,x01, fmaf(x02,x02, fmaf(x03,x03, sq0))));
    sq1 = fmaf(x10,x10, fmaf(x11,x11, fmaf(x12,x12, fmaf(x13,x13, sq1))));

#pragma unroll
    for (int k = 0; k < NROW; ++k){
      uint2 wu = *(const uint2*)(wb + (k << 10));
      float w0, w1, w2, w3;
      bf2_unpack(wu.x, w0, w1);
      bf2_unpack(wu.y, w2, w3);
      t[k][0] = fmaf(x00, w0, fmaf(x01, w1, fmaf(x02, w2, fmaf(x03, w3, t[k][0]))));
      t[k][1] = fmaf(x10, w0, fmaf(x11, w1, fmaf(x12, w2, fmaf(x13, w3, t[k][1]))));
    }
  }

  // cross-lane reductions (broadcast totals to all lanes)
  sum0 = wsum(sum0); sum1 = wsum(sum1);
  sq0  = wsum(sq0);  sq1  = wsum(sq1);
#pragma unroll
  for (int k = 0; k < NROW; ++k){ t[k][0] = wsum(t[k][0]); t[k][1] = wsum(t[k][1]); }

  // constants (uniform scalar loads)
  float a[NROW], bb[NROW];
#pragma unroll
  for (int k = 0; k < NROW; ++k){ a[k] = ws[WS_A + k]; bb[k] = ws[WS_B + k]; }
  const float it    = ws[WS_IT];
  const float alpha = ws[WS_ALPHA];
  const float mix0 = ws[WS_MIX], mix1 = ws[WS_MIX+1], mix2 = ws[WS_MIX+2];
  float M3[8][3];
#pragma unroll
  for (int r = 0; r < 8; ++r){
#pragma unroll
    for (int g = 0; g < 3; ++g) M3[r][g] = ws[WS_M3 + r*3 + g];
  }

  // per-lane hexagram row constants
  float sgn[6];
#pragma unroll
  for (int j = 0; j < 6; ++j) sgn[j] = ((lane >> (5 - j)) & 1) ? 1.0f : -1.0f;
  const float C5 = 0.44721359549995793f; // 1/sqrt(5)
  const float A0[6] = { C5,  C5,  C5,  C5,  C5, 0.f };
  const float A1[6] = {-0.5f, 0.5f, -0.5f, 0.f, 0.f, 0.5f};
  const float A2[6] = {-C5, -C5, 0.f, -C5, -C5, -C5};
  float cs0 = 0.f, cs1 = 0.f, cs2 = 0.f;
#pragma unroll
  for (int j = 0; j < 6; ++j){
    cs0 = fmaf(sgn[j], A0[j], cs0);
    cs1 = fmaf(sgn[j], A1[j], cs1);
    cs2 = fmaf(sgn[j], A2[j], cs2);
  }
  const int pc = __popc(lane);
  const float w7c = 1.0f / 7.0f;
  float wh0 = (pc >= 5) ? w7c  : 0.f;
  float wh1 = (pc == 3) ? 0.05f: 0.f;
  float wh2 = (pc <= 1) ? w7c  : 0.f;
  float m60 = (1.f - alpha)*cs0 + alpha*wh0;
  float m61 = (1.f - alpha)*cs1 + alpha*wh1;
  float m62 = (1.f - alpha)*cs2 + alpha*wh2;

  float hsum = 0.f, ga0 = 0.f, ga1 = 0.f, ga2 = 0.f;

#pragma unroll
  for (int j = 0; j < 2; ++j){
    const int tok = tok0 + j;
    float sumj = j ? sum1 : sum0;
    float sqj  = j ? sq1  : sq0;
    float mean = sumj * (1.0f / D);
    float var  = fmaf(sqj, 1.0f / D, -mean * mean);
    float rr   = rsqrtf(var + 1e-5f);
    float u[NROW];
#pragma unroll
    for (int k = 0; k < NROW; ++k){
      float d = fmaf(-mean, a[k], t[k][j]);
      u[k] = tanh_fast(fmaf(rr, d, bb[k]));
    }

    // ---- Q2 ----
    float p01 = u[0] + u[1], m01 = u[0] - u[1];
    float l0 = -p01*it, l1 = -m01*it, l2 = m01*it, l3 = p01*it;
    float mx2 = fmaxf(fmaxf(l0, l1), fmaxf(l2, l3));
    float e0 = __expf(l0-mx2), e1 = __expf(l1-mx2), e2 = __expf(l2-mx2), e3 = __expf(l3-mx2);
    float i2 = rcp_fast(e0 + e1 + e2 + e3);
    float s2g0 = e3 * i2, s2g1 = (e1 + e2) * i2, s2g2 = e0 * i2;

    // ---- Q3 ----
    float l3v[8]; float mx3 = -1e30f;
#pragma unroll
    for (int v = 0; v < 8; ++v){
      float acc = ((v & 4) ? u[2] : -u[2]) + ((v & 2) ? u[3] : -u[3]) + ((v & 1) ? u[4] : -u[4]);
      l3v[v] = acc * it;
      mx3 = fmaxf(mx3, l3v[v]);
    }
    float w3v[8]; float se3 = 0.f;
#pragma unroll
    for (int v = 0; v < 8; ++v){ w3v[v] = __expf(l3v[v] - mx3); se3 += w3v[v]; }
    float i3 = rcp_fast(se3);
    float s3g0 = 0.f, s3g1 = 0.f, s3g2 = 0.f;
#pragma unroll
    for (int v = 0; v < 8; ++v){
      s3g0 = fmaf(w3v[v], M3[v][0], s3g0);
      s3g1 = fmaf(w3v[v], M3[v][1], s3g1);
      s3g2 = fmaf(w3v[v], M3[v][2], s3g2);
    }
    s3g0 *= i3; s3g1 *= i3; s3g2 *= i3;

    // ---- Q6 (lane-parallel over 64 vertices) ----
    float lg = 0.f;
#pragma unroll
    for (int jj = 0; jj < 6; ++jj) lg = fmaf(sgn[jj], u[5 + jj], lg);
    lg *= it;
    float mx6 = wmax(lg);
    float p   = __expf(lg - mx6);
    float se6 = wsum(p);
    float hw  = p * rcp_fast(se6);
    hout[(size_t)tok * 64 + lane] = hw;
    hsum += hw;
    float s6g0 = wsum(hw * m60);
    float s6g1 = wsum(hw * m61);
    float s6g2 = wsum(hw * m62);

    // ---- combine + group softmax ----
    float g0 = mix0*s2g0 + mix1*s3g0 + mix2*s6g0;
    float g1 = mix0*s2g1 + mix1*s3g1 + mix2*s6g1;
    float g2 = mix0*s2g2 + mix1*s3g2 + mix2*s6g2;
    float gm = fmaxf(g0, fmaxf(g1, g2));
    float y0 = __expf(g0-gm), y1 = __expf(g1-gm), y2 = __expf(g2-gm);
    float gi = rcp_fast(y0 + y1 + y2);
    float gw0 = y0*gi, gw1 = y1*gi, gw2 = y2*gi;
    ga0 += gw0; ga1 += gw1; ga2 += gw2;
    if (lane < 3){
      float val = (lane == 0) ? gw0 : (lane == 1) ? gw1 : gw2;
      gout[(size_t)tok * 3 + lane] = val;
    }
  }

  // block partials for lb_loss
  lred[wid][lane] = hsum;
  if (lane < 3){
    float val = (lane == 0) ? ga0 : (lane == 1) ? ga1 : ga2;
    lred[wid][64 + lane] = val;
  }
  __syncthreads();
  if (tid < 67){
    float v = 0.f;
#pragma unroll
    for (int r = 0; r < 16; ++r) v += lred[r][tid];
    part[tid * K1_BLOCKS + blk] = v;
  }
}

// ---------------- k2: final reduction + lb_loss ----------------
__global__ __launch_bounds__(256) void k2_loss(const float* __restrict__ part,
                                               float* __restrict__ lout)
{
  __shared__ float sums[68];
  const int tid = threadIdx.x;
  const int lane = tid & 63;
  const int wid  = tid >> 6;
  for (int jv = wid; jv < 67; jv += 4){
    const float* p = part + jv * K1_BLOCKS;
    float v = 0.f;
#pragma unroll
    for (int b = 0; b < K1_BLOCKS / 64; ++b) v += p[lane + b * 64];
    v = wsum(v);
    if (lane == 0) sums[jv] = v;
  }
  __syncthreads();
  if (wid == 0){
    const float inv = 1.0f / (float)NTOK;
    float mh = sums[lane] * inv;
    float term = 0.1f * mh * logf(mh + 1e-8f);
    if (lane < 3){
      float mg = sums[64 + lane] * inv;
      term += mg * logf(mg + 1e-8f);
    }
    float L = wsum(term);
    if (lane == 0) lout[0] = L;
  }
}

extern "C" void kernel_launch(void* const* d_in, const int* in_sizes, int n_in,
                              void* d_out, int out_size, void* d_ws, size_t ws_size,
                              hipStream_t stream)
{
  const float* x             = (const float*)d_in[0];
  const float* ln_w          = (const float*)d_in[1];
  const float* ln_b          = (const float*)d_in[2];
  const float* w_q2          = (const float*)d_in[3];
  const float* w_q3          = (const float*)d_in[4];
  const float* w_q6          = (const float*)d_in[5];
  const float* log_temp      = (const float*)d_in[6];
  const float* log_scale_mix = (const float*)d_in[7];
  const float* q3_to_group   = (const float*)d_in[8];
  const float* log_wht_mix   = (const float*)d_in[9];

  float* out  = (float*)d_out;
  float* gout = out;                                        // (B,T,3)
  float* hout = out + (size_t)NTOK * 3;                     // (B,T,64)
  float* lout = out + (size_t)NTOK * 3 + (size_t)NTOK * 64; // scalar
  float* ws   = (float*)d_ws;

  k0_prep<<<12, 256, 0, stream>>>(ln_w, ln_b, w_q2, w_q3, w_q6,
                                  log_temp, log_scale_mix, q3_to_group, log_wht_mix, ws);
  k1_main<<<K1_BLOCKS, 1024, 0, stream>>>(x, ws, gout, hout, ws + WS_PART);
  k2_loss<<<1, 256, 0, stream>>>(ws + WS_PART, lout);
}

// Round 6
// 65.785 us; speedup vs baseline: 1.6540x; 1.1307x over previous
//
#include <hip/hip_runtime.h>
#include <math.h>

#define D 2048
#define NTOK 16384
#define NROW 11
#define MROWS_U32 (NROW * D / 2)   // 11264 uints = 44 KB (packed 2xbf16)
#define K1_BLOCKS 4096
#define K1_THREADS 256

// ws layout (4-byte units):
// [0..10] a_k   [16..26] b_k   [32] inv_temp  [33] alpha  [34..36] mix
// [40..63] M3 (8x3)  [64 .. 64+11264) packed-bf16 W'  [WS_PART ..) partials [67][4096]
#define WS_A 0
#define WS_B 16
#define WS_IT 32
#define WS_ALPHA 33
#define WS_MIX 34
#define WS_M3 40
#define WS_MERGED 64
#define WS_PART (WS_MERGED + MROWS_U32)

__device__ __forceinline__ float wsum(float v){
#pragma unroll
  for (int m = 1; m < 64; m <<= 1) v += __shfl_xor(v, m, 64);
  return v;
}
__device__ __forceinline__ float wmax(float v){
#pragma unroll
  for (int m = 1; m < 64; m <<= 1) v = fmaxf(v, __shfl_xor(v, m, 64));
  return v;
}
__device__ __forceinline__ float rcp_fast(float x){ return __builtin_amdgcn_rcpf(x); }
__device__ __forceinline__ float tanh_fast(float x){
  float e = __expf(2.0f * x);
  return 1.0f - 2.0f * rcp_fast(e + 1.0f);
}
// round-to-nearest-even f32 -> bf16 (upper 16 bits)
__device__ __forceinline__ unsigned int bf16_rne(float f){
  unsigned int u = __float_as_uint(f);
  return (u + 0x7fffu + ((u >> 16) & 1u)) >> 16;
}
__device__ __forceinline__ void bf2_unpack(unsigned int u, float &a, float &b){
  a = __uint_as_float(u << 16);          // low half  = even element
  b = __uint_as_float(u & 0xffff0000u);  // high half = odd element
}

// ---------------- k0: merge rows (bf16-packed) + constants (12 blocks) ----------------
__global__ __launch_bounds__(256) void k0_prep(
    const float* __restrict__ ln_w, const float* __restrict__ ln_b,
    const float* __restrict__ w_q2, const float* __restrict__ w_q3,
    const float* __restrict__ w_q6,
    const float* __restrict__ log_temp, const float* __restrict__ log_scale_mix,
    const float* __restrict__ q3_to_group, const float* __restrict__ log_wht_mix,
    float* __restrict__ ws)
{
  const int tid = threadIdx.x;
  const int k = blockIdx.x;
  unsigned int* wsu = (unsigned int*)ws;
  if (k < NROW){
    const float* row = (k < 2) ? (w_q2 + (size_t)k * D)
                     : (k < 5) ? (w_q3 + (size_t)(k - 2) * D)
                               : (w_q6 + (size_t)(k - 5) * D);
    float pa = 0.f, pb = 0.f;
    for (int i = tid * 2; i < D; i += 512){
      float w0 = row[i], w1 = row[i + 1];
      unsigned int b0 = bf16_rne(ln_w[i] * w0);
      unsigned int b1 = bf16_rne(ln_w[i + 1] * w1);
      // a_k accumulated from ROUNDED values (consistent with k1's dot)
      pa += __uint_as_float(b0 << 16) + __uint_as_float(b1 << 16);
      pb = fmaf(ln_b[i], w0, pb);
      pb = fmaf(ln_b[i + 1], w1, pb);
      wsu[WS_MERGED + k * 1024 + i / 2] = (b1 << 16) | b0;
    }
    __shared__ float red[8];
    pa = wsum(pa); pb = wsum(pb);
    if ((tid & 63) == 0){ red[tid >> 6] = pa; red[4 + (tid >> 6)] = pb; }
    __syncthreads();
    if (tid == 0){
      ws[WS_A + k] = red[0] + red[1] + red[2] + red[3];
      ws[WS_B + k] = red[4] + red[5] + red[6] + red[7];
    }
  } else if (tid == 0){
    float t = __expf(log_temp[0]);
    t = fminf(fmaxf(t, 0.1f), 5.0f);
    ws[WS_IT] = 1.0f / t;
    ws[WS_ALPHA] = 1.0f / (1.0f + __expf(-log_wht_mix[0]));
    float m0 = log_scale_mix[0], m1 = log_scale_mix[1], m2 = log_scale_mix[2];
    float mm = fmaxf(m0, fmaxf(m1, m2));
    float e0 = __expf(m0 - mm), e1 = __expf(m1 - mm), e2 = __expf(m2 - mm);
    float inv = 1.0f / (e0 + e1 + e2);
    ws[WS_MIX + 0] = e0 * inv; ws[WS_MIX + 1] = e1 * inv; ws[WS_MIX + 2] = e2 * inv;
    for (int r = 0; r < 8; ++r){
      float v0 = q3_to_group[r*3+0], v1 = q3_to_group[r*3+1], v2 = q3_to_group[r*3+2];
      float mx = fmaxf(v0, fmaxf(v1, v2));
      float f0 = __expf(v0 - mx), f1 = __expf(v1 - mx), f2 = __expf(v2 - mx);
      float iv = 1.0f / (f0 + f1 + f2);
      ws[WS_M3 + r*3 + 0] = f0 * iv;
      ws[WS_M3 + r*3 + 1] = f1 * iv;
      ws[WS_M3 + r*3 + 2] = f2 * iv;
    }
  }
}

// ---------------- k1: main per-token kernel ----------------
// 4096 blocks x 256 threads (4 waves). ONE token per wave: lane holds the
// whole token row in xa[8] (32 VGPR), loads issued BEFORE W'-staging so the
// staging + barrier hides all global latency. Compute phase is pure LDS+VALU.
__global__ __launch_bounds__(256) void k1_main(
    const float* __restrict__ x, const float* __restrict__ ws,
    float* __restrict__ gout, float* __restrict__ hout, float* __restrict__ part)
{
  __shared__ unsigned int sW[MROWS_U32];
  __shared__ float lred[4][68];
  const int tid  = threadIdx.x;
  const int lane = tid & 63;
  const int wid  = tid >> 6;
  const int blk  = blockIdx.x;
  const int tok  = blk * 4 + wid;

  // issue the whole token row (8 x float4) -- latency overlapped with staging
  const float* xp = x + (size_t)tok * D + lane * 4;
  float4 xa0 = *(const float4*)(xp + 0*256);
  float4 xa1 = *(const float4*)(xp + 1*256);
  float4 xa2 = *(const float4*)(xp + 2*256);
  float4 xa3 = *(const float4*)(xp + 3*256);
  float4 xa4 = *(const float4*)(xp + 4*256);
  float4 xa5 = *(const float4*)(xp + 5*256);
  float4 xa6 = *(const float4*)(xp + 6*256);
  float4 xa7 = *(const float4*)(xp + 7*256);

  // stage packed W' into LDS (2816 uint4 / 256 threads = 11 iters)
  {
    const uint4* src = (const uint4*)((const unsigned int*)ws + WS_MERGED);
    uint4* dst = (uint4*)sW;
#pragma unroll
    for (int i = 0; i < 11; ++i) dst[tid + i * 256] = src[tid + i * 256];
  }
  __syncthreads();   // drains staging AND xa loads

  float sum = 0.f, sq = 0.f;
  float t[NROW];
#pragma unroll
  for (int k = 0; k < NROW; ++k) t[k] = 0.f;

  const float4* xav[8] = {&xa0,&xa1,&xa2,&xa3,&xa4,&xa5,&xa6,&xa7};
#pragma unroll
  for (int c = 0; c < 8; ++c){
    const float4 xv = *xav[c];
    const float x0 = xv.x, x1 = xv.y, x2 = xv.z, x3 = xv.w;
    sum += (x0 + x1) + (x2 + x3);
    sq = fmaf(x0,x0, fmaf(x1,x1, fmaf(x2,x2, fmaf(x3,x3, sq))));
    const unsigned int* wb = sW + (c << 7) + lane * 2;
#pragma unroll
    for (int k = 0; k < NROW; ++k){
      uint2 wu = *(const uint2*)(wb + (k << 10));
      float w0, w1, w2, w3;
      bf2_unpack(wu.x, w0, w1);
      bf2_unpack(wu.y, w2, w3);
      t[k] = fmaf(x0, w0, fmaf(x1, w1, fmaf(x2, w2, fmaf(x3, w3, t[k]))));
    }
  }

  // cross-lane reductions (broadcast totals to all lanes)
  sum = wsum(sum); sq = wsum(sq);
#pragma unroll
  for (int k = 0; k < NROW; ++k) t[k] = wsum(t[k]);

  // constants (uniform scalar loads)
  float a[NROW], bb[NROW];
#pragma unroll
  for (int k = 0; k < NROW; ++k){ a[k] = ws[WS_A + k]; bb[k] = ws[WS_B + k]; }
  const float it    = ws[WS_IT];
  const float alpha = ws[WS_ALPHA];
  const float mix0 = ws[WS_MIX], mix1 = ws[WS_MIX+1], mix2 = ws[WS_MIX+2];

  // per-lane hexagram row constants
  float sgn[6];
#pragma unroll
  for (int j = 0; j < 6; ++j) sgn[j] = ((lane >> (5 - j)) & 1) ? 1.0f : -1.0f;
  const float C5 = 0.44721359549995793f; // 1/sqrt(5)
  const float A0[6] = { C5,  C5,  C5,  C5,  C5, 0.f };
  const float A1[6] = {-0.5f, 0.5f, -0.5f, 0.f, 0.f, 0.5f};
  const float A2[6] = {-C5, -C5, 0.f, -C5, -C5, -C5};
  float cs0 = 0.f, cs1 = 0.f, cs2 = 0.f;
#pragma unroll
  for (int j = 0; j < 6; ++j){
    cs0 = fmaf(sgn[j], A0[j], cs0);
    cs1 = fmaf(sgn[j], A1[j], cs1);
    cs2 = fmaf(sgn[j], A2[j], cs2);
  }
  const int pc = __popc(lane);
  const float w7c = 1.0f / 7.0f;
  float wh0 = (pc >= 5) ? w7c  : 0.f;
  float wh1 = (pc == 3) ? 0.05f: 0.f;
  float wh2 = (pc <= 1) ? w7c  : 0.f;
  float m60 = (1.f - alpha)*cs0 + alpha*wh0;
  float m61 = (1.f - alpha)*cs1 + alpha*wh1;
  float m62 = (1.f - alpha)*cs2 + alpha*wh2;

  // LayerNorm scalars + logits
  float mean = sum * (1.0f / D);
  float var  = fmaf(sq, 1.0f / D, -mean * mean);
  float rr   = rsqrtf(var + 1e-5f);
  float u[NROW];
#pragma unroll
  for (int k = 0; k < NROW; ++k){
    float d = fmaf(-mean, a[k], t[k]);
    u[k] = tanh_fast(fmaf(rr, d, bb[k]));
  }

  // ---- Q2 ----
  float p01 = u[0] + u[1], m01 = u[0] - u[1];
  float l0 = -p01*it, l1 = -m01*it, l2 = m01*it, l3 = p01*it;
  float mx2 = fmaxf(fmaxf(l0, l1), fmaxf(l2, l3));
  float e0 = __expf(l0-mx2), e1 = __expf(l1-mx2), e2 = __expf(l2-mx2), e3 = __expf(l3-mx2);
  float i2 = rcp_fast(e0 + e1 + e2 + e3);
  float s2g0 = e3 * i2, s2g1 = (e1 + e2) * i2, s2g2 = e0 * i2;

  // ---- Q3 ----
  float M3r[8][3];
#pragma unroll
  for (int r = 0; r < 8; ++r){
#pragma unroll
    for (int g = 0; g < 3; ++g) M3r[r][g] = ws[WS_M3 + r*3 + g];
  }
  float l3v[8]; float mx3 = -1e30f;
#pragma unroll
  for (int v = 0; v < 8; ++v){
    float acc = ((v & 4) ? u[2] : -u[2]) + ((v & 2) ? u[3] : -u[3]) + ((v & 1) ? u[4] : -u[4]);
    l3v[v] = acc * it;
    mx3 = fmaxf(mx3, l3v[v]);
  }
  float w3v[8]; float se3 = 0.f;
#pragma unroll
  for (int v = 0; v < 8; ++v){ w3v[v] = __expf(l3v[v] - mx3); se3 += w3v[v]; }
  float i3 = rcp_fast(se3);
  float s3g0 = 0.f, s3g1 = 0.f, s3g2 = 0.f;
#pragma unroll
  for (int v = 0; v < 8; ++v){
    s3g0 = fmaf(w3v[v], M3r[v][0], s3g0);
    s3g1 = fmaf(w3v[v], M3r[v][1], s3g1);
    s3g2 = fmaf(w3v[v], M3r[v][2], s3g2);
  }
  s3g0 *= i3; s3g1 *= i3; s3g2 *= i3;

  // ---- Q6 (lane-parallel over 64 vertices) ----
  float lg = 0.f;
#pragma unroll
  for (int jj = 0; jj < 6; ++jj) lg = fmaf(sgn[jj], u[5 + jj], lg);
  lg *= it;
  float mx6 = wmax(lg);
  float p   = __expf(lg - mx6);
  float se6 = wsum(p);
  float hw  = p * rcp_fast(se6);
  hout[(size_t)tok * 64 + lane] = hw;
  float s6g0 = wsum(hw * m60);
  float s6g1 = wsum(hw * m61);
  float s6g2 = wsum(hw * m62);

  // ---- combine + group softmax ----
  float g0 = mix0*s2g0 + mix1*s3g0 + mix2*s6g0;
  float g1 = mix0*s2g1 + mix1*s3g1 + mix2*s6g1;
  float g2 = mix0*s2g2 + mix1*s3g2 + mix2*s6g2;
  float gm = fmaxf(g0, fmaxf(g1, g2));
  float y0 = __expf(g0-gm), y1 = __expf(g1-gm), y2 = __expf(g2-gm);
  float gi = rcp_fast(y0 + y1 + y2);
  float gw0 = y0*gi, gw1 = y1*gi, gw2 = y2*gi;
  if (lane < 3){
    float val = (lane == 0) ? gw0 : (lane == 1) ? gw1 : gw2;
    gout[(size_t)tok * 3 + lane] = val;
  }

  // block partials for lb_loss
  lred[wid][lane] = hw;
  if (lane < 3){
    float val = (lane == 0) ? gw0 : (lane == 1) ? gw1 : gw2;
    lred[wid][64 + lane] = val;
  }
  __syncthreads();
  if (tid < 67){
    float v = lred[0][tid] + lred[1][tid] + lred[2][tid] + lred[3][tid];
    part[(size_t)tid * K1_BLOCKS + blk] = v;
  }
}

// ---------------- k2: final reduction + lb_loss ----------------
// 1024 threads = 16 waves; each wave owns jv rows (strided), float4 loads.
__global__ __launch_bounds__(1024) void k2_loss(const float* __restrict__ part,
                                                float* __restrict__ lout)
{
  __shared__ float sums[68];
  const int tid = threadIdx.x;
  const int lane = tid & 63;
  const int wid  = tid >> 6;
  for (int jv = wid; jv < 67; jv += 16){
    const float4* p = (const float4*)(part + (size_t)jv * K1_BLOCKS);
    float v = 0.f;
#pragma unroll
    for (int b = 0; b < K1_BLOCKS / 256; ++b){
      float4 q = p[lane + b * 64];
      v += (q.x + q.y) + (q.z + q.w);
    }
    v = wsum(v);
    if (lane == 0) sums[jv] = v;
  }
  __syncthreads();
  if (wid == 0){
    const float inv = 1.0f / (float)NTOK;
    float mh = sums[lane] * inv;
    float term = 0.1f * mh * logf(mh + 1e-8f);
    if (lane < 3){
      float mg = sums[64 + lane] * inv;
      term += mg * logf(mg + 1e-8f);
    }
    float L = wsum(term);
    if (lane == 0) lout[0] = L;
  }
}

extern "C" void kernel_launch(void* const* d_in, const int* in_sizes, int n_in,
                              void* d_out, int out_size, void* d_ws, size_t ws_size,
                              hipStream_t stream)
{
  const float* x             = (const float*)d_in[0];
  const float* ln_w          = (const float*)d_in[1];
  const float* ln_b          = (const float*)d_in[2];
  const float* w_q2          = (const float*)d_in[3];
  const float* w_q3          = (const float*)d_in[4];
  const float* w_q6          = (const float*)d_in[5];
  const float* log_temp      = (const float*)d_in[6];
  const float* log_scale_mix = (const float*)d_in[7];
  const float* q3_to_group   = (const float*)d_in[8];
  const float* log_wht_mix   = (const float*)d_in[9];

  float* out  = (float*)d_out;
  float* gout = out;                                        // (B,T,3)
  float* hout = out + (size_t)NTOK * 3;                     // (B,T,64)
  float* lout = out + (size_t)NTOK * 3 + (size_t)NTOK * 64; // scalar
  float* ws   = (float*)d_ws;

  k0_prep<<<12, 256, 0, stream>>>(ln_w, ln_b, w_q2, w_q3, w_q6,
                                  log_temp, log_scale_mix, q3_to_group, log_wht_mix, ws);
  k1_main<<<K1_BLOCKS, K1_THREADS, 0, stream>>>(x, ws, gout, hout, ws + WS_PART);
  k2_loss<<<1, 1024, 0, stream>>>(ws + WS_PART, lout);
}